// Round 13
// baseline (850.419 us; speedup 1.0000x reference)
//
#include <hip/hip_runtime.h>
#include <hip/hip_bf16.h>

// FrequencyAwareSumAttention — round 13: occupancy attack on attn.
// (1) K1 writes V TRANSPOSED vT[head][d][t] -> PV B-frags become single 16B
//     global loads; the 32KB Vt LDS buffer + its transpose staging (source of
//     the 5.19M bank conflicts) are deleted.
// (2) attn LDS 79->46KB and __launch_bounds__(256,3) -> 3 blocks/CU, 12 waves/CU;
//     all 544 blocks co-resident (no second generation).
// K0/K2/K4 unchanged from round 12.

#define SCALE 0.125f
#define LSTR 72

typedef __attribute__((ext_vector_type(4))) float f32x4;
typedef __attribute__((ext_vector_type(8))) short bf16x8;
typedef __attribute__((ext_vector_type(8))) unsigned short u16x8;

__device__ __forceinline__ float bf2f(unsigned short u) {
  return __uint_as_float(((unsigned int)u) << 16);
}
__device__ __forceinline__ unsigned short f2bf(float f) {
  unsigned int u = __float_as_uint(f);
  u += 0x7FFFu + ((u >> 16) & 1u);
  return (unsigned short)(u >> 16);
}

// ---------------- K0a: x fp32 -> hi/lo bf16 planes ----------------
__global__ __launch_bounds__(256) void conv_x(
    const float* __restrict__ x, unsigned short* __restrict__ xh,
    unsigned short* __restrict__ xl) {
  const size_t i = ((size_t)blockIdx.x * 256 + threadIdx.x) * 8;
  float4 a = *(const float4*)(x + i);
  float4 b = *(const float4*)(x + i + 4);
  float vv[8] = {a.x, a.y, a.z, a.w, b.x, b.y, b.z, b.w};
  u16x8 hi, lo;
#pragma unroll
  for (int e = 0; e < 8; ++e) {
    unsigned short h = f2bf(vv[e]);
    hi[e] = h;
    lo[e] = f2bf(vv[e] - bf2f(h));
  }
  *(u16x8*)&xh[i] = hi;
  *(u16x8*)&xl[i] = lo;
}

// ---------------- K0b: w [K=512][N] -> transposed [N][512] hi/lo planes ----------
__global__ __launch_bounds__(256) void conv_wT(
    const float* __restrict__ w, unsigned short* __restrict__ th,
    unsigned short* __restrict__ tl, int N) {
  __shared__ float T[64][65];
  const int tid = threadIdx.x;
  const int nt = blockIdx.x * 64, kt = blockIdx.y * 64;
  for (int i = tid; i < 4096; i += 256) {
    const int r = i >> 6, c = i & 63;
    T[r][c] = w[(size_t)(kt + r) * N + nt + c];
  }
  __syncthreads();
  for (int i = tid; i < 4096; i += 256) {
    const int rn = i >> 6, ck = i & 63;
    const float v = T[ck][rn];
    const unsigned short h = f2bf(v);
    const size_t o = (size_t)(nt + rn) * 512 + kt + ck;
    th[o] = h;
    tl[o] = f2bf(v - bf2f(h));
  }
}

// ---------------- K1: qkv = x @ w_qkv (split-bf16 MFMA) -> bf16 planes ----------
// q/k: [head][t][d] hi+lo planes.  v: TRANSPOSED [head][d][t] hi plane.
__global__ __launch_bounds__(256, 2) void qkv_gemm(
    const unsigned short* __restrict__ xh, const unsigned short* __restrict__ xl,
    const unsigned short* __restrict__ wh, const unsigned short* __restrict__ wl,
    unsigned short* __restrict__ qh, unsigned short* __restrict__ ql,
    unsigned short* __restrict__ kh, unsigned short* __restrict__ kl,
    unsigned short* __restrict__ vt) {
  __shared__ __attribute__((aligned(16))) unsigned short Wt[2][128 * LSTR];
  __shared__ __attribute__((aligned(16))) unsigned short Xt[2][128 * LSTR];

  const int tid = threadIdx.x;
  const int bx = blockIdx.x, by = blockIdx.y;
  const int wid = tid >> 6, lane = tid & 63;
  const int lr = lane & 15, lg = lane >> 4;
  const int wr = wid >> 1, wc = wid & 1;
  const int srow = tid >> 3, skg = tid & 7;

  const unsigned short* xhp = xh + (size_t)(by * 128 + srow) * 512 + skg * 8;
  const unsigned short* xlp = xl + (size_t)(by * 128 + srow) * 512 + skg * 8;
  const unsigned short* whp = wh + (size_t)(bx * 128 + srow) * 512 + skg * 8;
  const unsigned short* wlp = wl + (size_t)(bx * 128 + srow) * 512 + skg * 8;

  u16x8 rxh[4], rxl[4], rwh[4], rwl[4];
  auto loadk = [&](int k0) {
#pragma unroll
    for (int it = 0; it < 4; ++it) {
      const size_t o = (size_t)(32 * it) * 512 + k0;
      rxh[it] = *(const u16x8*)(xhp + o);
      rxl[it] = *(const u16x8*)(xlp + o);
      rwh[it] = *(const u16x8*)(whp + o);
      rwl[it] = *(const u16x8*)(wlp + o);
    }
  };

  f32x4 acc[4][4];
#pragma unroll
  for (int nt = 0; nt < 4; ++nt)
#pragma unroll
    for (int mt = 0; mt < 4; ++mt) acc[nt][mt] = (f32x4){0.f, 0.f, 0.f, 0.f};

  loadk(0);
  for (int s = 0; s < 8; ++s) {
    if (s) __syncthreads();
#pragma unroll
    for (int it = 0; it < 4; ++it) {
      const int base = (srow + 32 * it) * LSTR + skg * 8;
      *(u16x8*)&Xt[0][base] = rxh[it];
      *(u16x8*)&Xt[1][base] = rxl[it];
      *(u16x8*)&Wt[0][base] = rwh[it];
      *(u16x8*)&Wt[1][base] = rwl[it];
    }
    __syncthreads();
    if (s < 7) loadk((s + 1) * 64);
#pragma unroll
    for (int kh2 = 0; kh2 < 2; ++kh2) {
      const int kbase = kh2 * 32 + lg * 8;
      bf16x8 Ah[4], Al[4], Bh[4], Bl[4];
#pragma unroll
      for (int nt = 0; nt < 4; ++nt) {
        const int n = wr * 64 + nt * 16 + lr;
        Ah[nt] = *(bf16x8*)&Wt[0][n * LSTR + kbase];
        Al[nt] = *(bf16x8*)&Wt[1][n * LSTR + kbase];
      }
#pragma unroll
      for (int mt = 0; mt < 4; ++mt) {
        const int m = wc * 64 + mt * 16 + lr;
        Bh[mt] = *(bf16x8*)&Xt[0][m * LSTR + kbase];
        Bl[mt] = *(bf16x8*)&Xt[1][m * LSTR + kbase];
      }
#pragma unroll
      for (int nt = 0; nt < 4; ++nt)
#pragma unroll
        for (int mt = 0; mt < 4; ++mt) {
          acc[nt][mt] = __builtin_amdgcn_mfma_f32_16x16x32_bf16(Ah[nt], Bh[mt], acc[nt][mt], 0, 0, 0);
          acc[nt][mt] = __builtin_amdgcn_mfma_f32_16x16x32_bf16(Ah[nt], Bl[mt], acc[nt][mt], 0, 0, 0);
          acc[nt][mt] = __builtin_amdgcn_mfma_f32_16x16x32_bf16(Al[nt], Bh[mt], acc[nt][mt], 0, 0, 0);
        }
    }
  }

#pragma unroll
  for (int mt = 0; mt < 4; ++mt) {
    const int m = by * 128 + wc * 64 + mt * 16 + lr;
    const int jj = m % 17;
    const int bt = m / 17;
    const int t = bt & 255;
    const int b = bt >> 8;
#pragma unroll
    for (int nt = 0; nt < 4; ++nt) {
      const int c = bx * 128 + wr * 64 + nt * 16 + lg * 4;
      const int qi = c >> 9;
      const int h = (c >> 6) & 7;
      const int dd = c & 63;
      const size_t hdbase = ((size_t)((b * 8 + h) * 17 + jj)) * 16384;
      float a0 = acc[nt][mt][0], a1 = acc[nt][mt][1], a2 = acc[nt][mt][2],
            a3 = acc[nt][mt][3];
      ushort4 hi4 = make_ushort4(f2bf(a0), f2bf(a1), f2bf(a2), f2bf(a3));
      if (qi == 2) {
        // vT[d][t]: 4 scalar stores; 16 lr lanes are consecutive t -> coalesced
        vt[hdbase + (size_t)(dd + 0) * 256 + t] = hi4.x;
        vt[hdbase + (size_t)(dd + 1) * 256 + t] = hi4.y;
        vt[hdbase + (size_t)(dd + 2) * 256 + t] = hi4.z;
        vt[hdbase + (size_t)(dd + 3) * 256 + t] = hi4.w;
      } else {
        ushort4 lo4 = make_ushort4(f2bf(a0 - bf2f(hi4.x)), f2bf(a1 - bf2f(hi4.y)),
                                   f2bf(a2 - bf2f(hi4.z)), f2bf(a3 - bf2f(hi4.w)));
        unsigned short* dh = qi ? kh : qh;
        unsigned short* dl = qi ? kl : ql;
        *(ushort4*)&dh[hdbase + t * 64 + dd] = hi4;
        *(ushort4*)&dl[hdbase + t * 64 + dd] = lo4;
      }
    }
  }
}

// ---------------- K2: MFMA DFT from bf16 planes + af GEMM + softmax -> af bf16 ----
__global__ __launch_bounds__(256) void freq_kernel(
    const unsigned short* __restrict__ qhp, const unsigned short* __restrict__ qlp,
    const unsigned short* __restrict__ khp, const unsigned short* __restrict__ klp,
    unsigned short* __restrict__ af_out) {
  __shared__ __attribute__((aligned(16))) unsigned short qT[2][64 * 256];
  __shared__ __attribute__((aligned(16))) unsigned short QF[4][64 * 64];
  __shared__ __attribute__((aligned(16))) unsigned short KF[4][64 * 64];

  const int tid = threadIdx.x;
  const int head = blockIdx.x;
  const int w = tid >> 6, lane = tid & 63;
  const int lr = lane & 15, lg = lane >> 4;
  const int f0 = w << 4;

  bf16x8 Ech[8], Ecl[8], Esh[8], Esl[8];
  {
    const int f = f0 + lr;
#pragma unroll
    for (int kb = 0; kb < 8; ++kb) {
      bf16x8 ch, cl, sh, sl;
#pragma unroll
      for (int i = 0; i < 8; ++i) {
        int t = kb * 32 + lg * 8 + i;
        int idx = (f * t) & 255;
        float s, c;
        __sincosf((float)idx * 0.02454369260617026f, &s, &c);
        unsigned short chh = f2bf(c);
        unsigned short shh = f2bf(s);
        ch[i] = (short)chh;
        cl[i] = (short)f2bf(c - bf2f(chh));
        sh[i] = (short)shh;
        sl[i] = (short)f2bf(s - bf2f(shh));
      }
      Ech[kb] = ch; Ecl[kb] = cl; Esh[kb] = sh; Esl[kb] = sl;
    }
  }

  for (int pass = 0; pass < 2; ++pass) {
    const unsigned short* sh_ = (pass ? khp : qhp) + head * 16384;
    const unsigned short* sl_ = (pass ? klp : qlp) + head * 16384;
    __syncthreads();
    for (int i = tid; i < 4096; i += 256) {
      int t = i >> 4, dq = i & 15;
      ushort4 hv = *(const ushort4*)&sh_[t * 64 + dq * 4];
      ushort4 lv = *(const ushort4*)&sl_[t * 64 + dq * 4];
      unsigned short hvv[4] = {hv.x, hv.y, hv.z, hv.w};
      unsigned short lvv[4] = {lv.x, lv.y, lv.z, lv.w};
#pragma unroll
      for (int c = 0; c < 4; ++c) {
        int d = dq * 4 + c;
        int byo = d * 512 + ((t * 2) ^ ((d & 31) << 4));
        *(unsigned short*)((char*)qT[0] + byo) = hvv[c];
        *(unsigned short*)((char*)qT[1] + byo) = lvv[c];
      }
    }
    __syncthreads();

    f32x4 ar[4], ai[4];
#pragma unroll
    for (int nt = 0; nt < 4; ++nt) {
      ar[nt] = (f32x4){0.f, 0.f, 0.f, 0.f};
      ai[nt] = (f32x4){0.f, 0.f, 0.f, 0.f};
    }
#pragma unroll
    for (int kb = 0; kb < 8; ++kb) {
#pragma unroll
      for (int nt = 0; nt < 4; ++nt) {
        const int d = nt * 16 + lr;
        const int byo = d * 512 + ((kb * 64 + lg * 16) ^ ((d & 31) << 4));
        bf16x8 bh = *(bf16x8*)((char*)qT[0] + byo);
        bf16x8 bl = *(bf16x8*)((char*)qT[1] + byo);
        ar[nt] = __builtin_amdgcn_mfma_f32_16x16x32_bf16(Ech[kb], bh, ar[nt], 0, 0, 0);
        ar[nt] = __builtin_amdgcn_mfma_f32_16x16x32_bf16(Ech[kb], bl, ar[nt], 0, 0, 0);
        ar[nt] = __builtin_amdgcn_mfma_f32_16x16x32_bf16(Ecl[kb], bh, ar[nt], 0, 0, 0);
        ai[nt] = __builtin_amdgcn_mfma_f32_16x16x32_bf16(Esh[kb], bh, ai[nt], 0, 0, 0);
        ai[nt] = __builtin_amdgcn_mfma_f32_16x16x32_bf16(Esh[kb], bl, ai[nt], 0, 0, 0);
        ai[nt] = __builtin_amdgcn_mfma_f32_16x16x32_bf16(Esl[kb], bh, ai[nt], 0, 0, 0);
      }
    }
    unsigned short(*DST)[64 * 64] = pass ? KF : QF;
#pragma unroll
    for (int nt = 0; nt < 4; ++nt) {
#pragma unroll
      for (int j = 0; j < 4; ++j) {
        const int f = f0 + lg * 4 + j;
        const int d = nt * 16 + lr;
        const int byo = f * 128 + ((d * 2) ^ ((f & 7) << 4));
        float vr = ar[nt][j], vi = ai[nt][j];
        unsigned short rh = f2bf(vr);
        unsigned short ih = f2bf(vi);
        *(unsigned short*)((char*)DST[0] + byo) = rh;
        *(unsigned short*)((char*)DST[1] + byo) = f2bf(vr - bf2f(rh));
        *(unsigned short*)((char*)DST[2] + byo) = ih;
        *(unsigned short*)((char*)DST[3] + byo) = f2bf(vi - bf2f(ih));
      }
    }
  }
  __syncthreads();

  f32x4 acc[4];
#pragma unroll
  for (int nt = 0; nt < 4; ++nt) acc[nt] = (f32x4){0.f, 0.f, 0.f, 0.f};
#pragma unroll
  for (int kb = 0; kb < 2; ++kb) {
    const int fA = f0 + lr;
    const int abyo = fA * 128 + ((kb * 64 + lg * 16) ^ ((fA & 7) << 4));
    bf16x8 arh = *(bf16x8*)((char*)QF[0] + abyo);
    bf16x8 arl = *(bf16x8*)((char*)QF[1] + abyo);
    bf16x8 aih = *(bf16x8*)((char*)QF[2] + abyo);
    bf16x8 ail = *(bf16x8*)((char*)QF[3] + abyo);
#pragma unroll
    for (int nt = 0; nt < 4; ++nt) {
      const int g = nt * 16 + lr;
      const int bbyo = g * 128 + ((kb * 64 + lg * 16) ^ ((g & 7) << 4));
      bf16x8 brh = *(bf16x8*)((char*)KF[0] + bbyo);
      bf16x8 brl = *(bf16x8*)((char*)KF[1] + bbyo);
      bf16x8 bih = *(bf16x8*)((char*)KF[2] + bbyo);
      bf16x8 bil = *(bf16x8*)((char*)KF[3] + bbyo);
      acc[nt] = __builtin_amdgcn_mfma_f32_16x16x32_bf16(arh, brh, acc[nt], 0, 0, 0);
      acc[nt] = __builtin_amdgcn_mfma_f32_16x16x32_bf16(arh, brl, acc[nt], 0, 0, 0);
      acc[nt] = __builtin_amdgcn_mfma_f32_16x16x32_bf16(arl, brh, acc[nt], 0, 0, 0);
      acc[nt] = __builtin_amdgcn_mfma_f32_16x16x32_bf16(aih, bih, acc[nt], 0, 0, 0);
      acc[nt] = __builtin_amdgcn_mfma_f32_16x16x32_bf16(aih, bil, acc[nt], 0, 0, 0);
      acc[nt] = __builtin_amdgcn_mfma_f32_16x16x32_bf16(ail, bih, acc[nt], 0, 0, 0);
    }
  }

  unsigned short* outh = af_out + head * 4096;
#pragma unroll
  for (int j = 0; j < 4; ++j) {
    float m = fmaxf(fmaxf(acc[0][j], acc[1][j]), fmaxf(acc[2][j], acc[3][j]));
#pragma unroll
    for (int mask = 1; mask < 16; mask <<= 1) m = fmaxf(m, __shfl_xor(m, mask));
    float e[4];
    float rs = 0.f;
#pragma unroll
    for (int nt = 0; nt < 4; ++nt) {
      e[nt] = __expf((acc[nt][j] - m) * SCALE);
      rs += e[nt];
    }
#pragma unroll
    for (int mask = 1; mask < 16; mask <<= 1) rs += __shfl_xor(rs, mask);
    const float inv = 1.0f / rs;
    const int f = f0 + lg * 4 + j;
#pragma unroll
    for (int nt = 0; nt < 4; ++nt) outh[f * 64 + nt * 16 + lr] = f2bf(e[nt] * inv);
  }
}

// ---------------- K3: merged MFMA attention, V from global (no Vt LDS) ----------
__global__ __launch_bounds__(256, 3) void attn_kernel(
    const unsigned short* __restrict__ qhp, const unsigned short* __restrict__ khp,
    const unsigned short* __restrict__ vtp, const unsigned short* __restrict__ af,
    const float* __restrict__ att_map, const float* __restrict__ weight,
    const float* __restrict__ fgate, float* __restrict__ out_perm) {
  __shared__ unsigned short Ks[256 * 64];
  __shared__ unsigned short afl[64 * 66];
  __shared__ unsigned short Psc[4][16 * 40];

  const int tid = threadIdx.x;
  const int head = blockIdx.x;
  const int jj = head % 17;
  const int hb = head / 17;
  const int h = hb & 7;
  const int b = hb >> 3;
  const int w = tid >> 6, lane = tid & 63;
  const int lr = lane & 15, lg = lane >> 4;

  const float* amh = att_map + (size_t)head * 65536;
  const unsigned short* qbase = qhp + head * 16384;
  const unsigned short* vtb = vtp + head * 16384;

  // ---- issue tile-0 Q frag loads early (16B each, bf16 direct) ----
  bf16x8 rq[2];
  {
    const unsigned short* qrow = qbase + (w * 64 + lr) * 64 + lg * 8;
    rq[0] = *(const bf16x8*)(qrow);
    rq[1] = *(const bf16x8*)(qrow + 32);
  }

  // ---- stage K (16B-granule XOR swizzle copy) and afl ----
  const unsigned short* ksrc = khp + head * 16384;
  for (int i = tid; i < 2048; i += 256) {
    int s = i >> 3, dq8 = i & 7;
    u16x8 kv = *(const u16x8*)&ksrc[s * 64 + dq8 * 8];
    int koff = s * 128 + ((dq8 * 16) ^ ((s & 7) << 4));
    *(u16x8*)((char*)Ks + koff) = kv;
  }
  const unsigned short* asrc = af + head * 4096;
  for (int i = tid; i < 1024; i += 256) {
    int f = i >> 4, gq = (i & 15) << 2;
    *(ushort4*)&afl[f * 66 + gq] = *(const ushort4*)&asrc[f * 64 + gq];
  }
  __syncthreads();

  const float wv = weight[0];
  const float gate = 1.0f / (1.0f + __expf(-fgate[0]));
  unsigned short* psc = Psc[w];

  for (int tt = 0; tt < 4; ++tt) {
    const int tw = w * 64 + tt * 16;

    bf16x8 aq[2] = {rq[0], rq[1]};

    // ---- QK^T ----
    f32x4 S[16];
#pragma unroll
    for (int nt = 0; nt < 16; ++nt) {
      f32x4 accv = {0.f, 0.f, 0.f, 0.f};
#pragma unroll
      for (int kc = 0; kc < 2; ++kc) {
        int srow = nt * 16 + lr;
        int d0 = kc * 32 + lg * 8;
        int off = srow * 128 + ((d0 * 2) ^ ((srow & 7) << 4));
        bf16x8 bk = *(bf16x8*)((char*)Ks + off);
        accv = __builtin_amdgcn_mfma_f32_16x16x32_bf16(aq[kc], bk, accv, 0, 0, 0);
      }
      S[nt] = accv;
    }

    // ---- prefetch next tile's Q ----
    if (tt < 3) {
      const unsigned short* qrow = qbase + (tw + 16 + lr) * 64 + lg * 8;
      rq[0] = *(const bf16x8*)(qrow);
      rq[1] = *(const bf16x8*)(qrow + 32);
    }

    // ---- softmax (16-lane xor groups) ----
    float inv[4], mrow[4];
#pragma unroll
    for (int j = 0; j < 4; ++j) {
      float m = -1e30f;
#pragma unroll
      for (int nt = 0; nt < 16; ++nt) m = fmaxf(m, S[nt][j]);
#pragma unroll
      for (int mask = 1; mask < 16; mask <<= 1) m = fmaxf(m, __shfl_xor(m, mask));
      mrow[j] = m;
    }
#pragma unroll
    for (int j = 0; j < 4; ++j) {
      float rs = 0.f;
#pragma unroll
      for (int nt = 0; nt < 16; ++nt) {
        float e = __expf((S[nt][j] - mrow[j]) * SCALE);
        S[nt][j] = e;
        rs += e;
      }
#pragma unroll
      for (int mask = 1; mask < 16; mask <<= 1) rs += __shfl_xor(rs, mask);
      inv[j] = 1.0f / rs;
    }

    // ---- combine: interp(freq) + att_map (direct loads) + time softmax ----
#pragma unroll
    for (int j = 0; j < 4; ++j) {
      const int t = tw + lg * 4 + j;
      float srcf = fmaxf((t + 0.5f) * (129.0f / 256.0f) - 0.5f, 0.0f);
      int f0r = (int)srcf;
      float wf = srcf - (float)f0r;
      int f1r = f0r + 1;
      if (f1r > 128) f1r = 128;
      const bool v0 = (f0r < 64), v1 = (f1r < 64);
#pragma unroll
      for (int nt = 0; nt < 16; ++nt) {
        const int s = nt * 16 + lr;
        float am = amh[t * 256 + s];
        float srcg = fmaxf((s + 0.5f) * 0.25f - 0.5f, 0.0f);
        int g0 = (int)srcg;
        float wc = srcg - (float)g0;
        int g1 = g0 + 1;
        if (g1 > 63) g1 = 63;
        float fr = 0.f;
        if (v0)
          fr += (1.0f - wf) *
                (bf2f(afl[f0r * 66 + g0]) * (1.0f - wc) + bf2f(afl[f0r * 66 + g1]) * wc);
        if (v1)
          fr += wf *
                (bf2f(afl[f1r * 66 + g0]) * (1.0f - wc) + bf2f(afl[f1r * 66 + g1]) * wc);
        float pt = S[nt][j] * inv[j];
        S[nt][j] = wv * (gate * fr + (1.0f - gate) * pt) + (1.0f - wv) * am;
      }
    }

    // ---- PV: B-frags straight from global vT (16B contiguous, L1/L2-resident) ----
    f32x4 O[4];
#pragma unroll
    for (int dt = 0; dt < 4; ++dt) O[dt] = (f32x4){0.f, 0.f, 0.f, 0.f};
#pragma unroll
    for (int sb = 0; sb < 8; ++sb) {
#pragma unroll
      for (int half = 0; half < 2; ++half) {
        const int nt = sb * 2 + half;
#pragma unroll
        for (int j = 0; j < 4; ++j) {
          psc[(lg * 4 + j) * 40 + half * 16 + lr] = f2bf(S[nt][j]);
        }
      }
      bf16x8 pa = *(bf16x8*)&psc[lr * 40 + lg * 8];
      const int s0 = sb * 32 + lg * 8;
#pragma unroll
      for (int dt = 0; dt < 4; ++dt) {
        const int d = dt * 16 + lr;
        bf16x8 bv = *(const bf16x8*)&vtb[d * 256 + s0];
        O[dt] = __builtin_amdgcn_mfma_f32_16x16x32_bf16(pa, bv, O[dt], 0, 0, 0);
      }
    }

    // ---- write out_perm ----
#pragma unroll
    for (int j = 0; j < 4; ++j) {
      const int t = tw + lg * 4 + j;
      float* orow = out_perm + ((size_t)((b * 256 + t) * 17 + jj)) * 512 + h * 64;
#pragma unroll
      for (int dt = 0; dt < 4; ++dt) {
        orow[dt * 16 + lr] = O[dt][j];
      }
    }
  }
}

// ---------------- K4: d_out = out_perm @ w_proj + b_proj (split-bf16 MFMA) --------
__global__ __launch_bounds__(256, 2) void proj_gemm(
    const float* __restrict__ A,
    const unsigned short* __restrict__ wh, const unsigned short* __restrict__ wl,
    const float* __restrict__ bias, float* __restrict__ out) {
  __shared__ __attribute__((aligned(16))) unsigned short Wt[2][128 * LSTR];
  __shared__ __attribute__((aligned(16))) unsigned short Xt[2][128 * LSTR];

  const int tid = threadIdx.x;
  const int bx = blockIdx.x, by = blockIdx.y;
  const int wid = tid >> 6, lane = tid & 63;
  const int lr = lane & 15, lg = lane >> 4;
  const int wr = wid >> 1, wc = wid & 1;
  const int srow = tid >> 3, skg = tid & 7;

  const float* ap = A + (size_t)(by * 128 + srow) * 512 + skg * 8;
  const unsigned short* whp = wh + (size_t)(bx * 128 + srow) * 512 + skg * 8;
  const unsigned short* wlp = wl + (size_t)(bx * 128 + srow) * 512 + skg * 8;

  float4 rA[4][2];
  u16x8 rwh[4], rwl[4];
  auto loadk = [&](int k0) {
#pragma unroll
    for (int it = 0; it < 4; ++it) {
      const size_t o = (size_t)(32 * it) * 512 + k0;
      rA[it][0] = *(const float4*)(ap + o);
      rA[it][1] = *(const float4*)(ap + o + 4);
      rwh[it] = *(const u16x8*)(whp + o);
      rwl[it] = *(const u16x8*)(wlp + o);
    }
  };

  f32x4 acc[4][4];
#pragma unroll
  for (int nt = 0; nt < 4; ++nt)
#pragma unroll
    for (int mt = 0; mt < 4; ++mt) acc[nt][mt] = (f32x4){0.f, 0.f, 0.f, 0.f};

  loadk(0);
  for (int s = 0; s < 8; ++s) {
    if (s) __syncthreads();
#pragma unroll
    for (int it = 0; it < 4; ++it) {
      const int base = (srow + 32 * it) * LSTR + skg * 8;
      float vv[8] = {rA[it][0].x, rA[it][0].y, rA[it][0].z, rA[it][0].w,
                     rA[it][1].x, rA[it][1].y, rA[it][1].z, rA[it][1].w};
      u16x8 hi, lo;
#pragma unroll
      for (int e = 0; e < 8; ++e) {
        unsigned short h = f2bf(vv[e]);
        hi[e] = h;
        lo[e] = f2bf(vv[e] - bf2f(h));
      }
      *(u16x8*)&Xt[0][base] = hi;
      *(u16x8*)&Xt[1][base] = lo;
      *(u16x8*)&Wt[0][base] = rwh[it];
      *(u16x8*)&Wt[1][base] = rwl[it];
    }
    __syncthreads();
    if (s < 7) loadk((s + 1) * 64);
#pragma unroll
    for (int kh2 = 0; kh2 < 2; ++kh2) {
      const int kbase = kh2 * 32 + lg * 8;
      bf16x8 Ah[4], Al[4], Bh[4], Bl[4];
#pragma unroll
      for (int nt = 0; nt < 4; ++nt) {
        const int n = wr * 64 + nt * 16 + lr;
        Ah[nt] = *(bf16x8*)&Wt[0][n * LSTR + kbase];
        Al[nt] = *(bf16x8*)&Wt[1][n * LSTR + kbase];
      }
#pragma unroll
      for (int mt = 0; mt < 4; ++mt) {
        const int m = wc * 64 + mt * 16 + lr;
        Bh[mt] = *(bf16x8*)&Xt[0][m * LSTR + kbase];
        Bl[mt] = *(bf16x8*)&Xt[1][m * LSTR + kbase];
      }
#pragma unroll
      for (int nt = 0; nt < 4; ++nt)
#pragma unroll
        for (int mt = 0; mt < 4; ++mt) {
          acc[nt][mt] = __builtin_amdgcn_mfma_f32_16x16x32_bf16(Ah[nt], Bh[mt], acc[nt][mt], 0, 0, 0);
          acc[nt][mt] = __builtin_amdgcn_mfma_f32_16x16x32_bf16(Ah[nt], Bl[mt], acc[nt][mt], 0, 0, 0);
          acc[nt][mt] = __builtin_amdgcn_mfma_f32_16x16x32_bf16(Al[nt], Bh[mt], acc[nt][mt], 0, 0, 0);
        }
    }
  }

#pragma unroll
  for (int mt = 0; mt < 4; ++mt) {
    const int m = by * 128 + wc * 64 + mt * 16 + lr;
#pragma unroll
    for (int nt = 0; nt < 4; ++nt) {
      const int n = bx * 128 + wr * 64 + nt * 16 + lg * 4;
      float4 bi = *(const float4*)&bias[n];
      *(float4*)&out[(size_t)m * 512 + n] =
          make_float4(acc[nt][mt][0] + bi.x, acc[nt][mt][1] + bi.y,
                      acc[nt][mt][2] + bi.z, acc[nt][mt][3] + bi.w);
    }
  }
}

extern "C" void kernel_launch(void* const* d_in, const int* in_sizes, int n_in,
                              void* d_out, int out_size, void* d_ws, size_t ws_size,
                              hipStream_t stream) {
  (void)in_sizes; (void)n_in; (void)out_size; (void)ws_size;
  const float* x = (const float*)d_in[0];
  const float* att_map = (const float*)d_in[1];
  const float* weight = (const float*)d_in[2];
  const float* w_qkv = (const float*)d_in[3];
  const float* w_proj = (const float*)d_in[4];
  const float* b_proj = (const float*)d_in[5];
  const float* fgate = (const float*)d_in[6];
  float* out = (float*)d_out;

  char* ws = (char*)d_ws;
  const size_t PB = 17825792;  // one bf16 plane: 544*16384*2 B
  unsigned short* qh = (unsigned short*)(ws);
  unsigned short* ql = (unsigned short*)(ws + PB);
  unsigned short* kh = (unsigned short*)(ws + 2 * PB);
  unsigned short* kl = (unsigned short*)(ws + 3 * PB);
  unsigned short* vt = (unsigned short*)(ws + 4 * PB);
  unsigned short* af = (unsigned short*)(ws + 5 * PB);  // 544*4096 bf16
  char* base = ws + 5 * PB + 4456448;
  unsigned short* xh = (unsigned short*)(base);
  unsigned short* xl = (unsigned short*)(base + PB);
  float* out_perm = (float*)(base);  // alias xh/xl (disjoint lifetimes)
  unsigned short* wqh = (unsigned short*)(base + 35651584);
  unsigned short* wql = (unsigned short*)(base + 35651584 + 1572864);
  unsigned short* wph = (unsigned short*)(base + 35651584 + 2 * 1572864);
  unsigned short* wpl = (unsigned short*)(base + 35651584 + 2 * 1572864 + 524288);

  conv_x<<<4352, 256, 0, stream>>>(x, xh, xl);
  conv_wT<<<dim3(24, 8), 256, 0, stream>>>(w_qkv, wqh, wql, 1536);
  conv_wT<<<dim3(8, 8), 256, 0, stream>>>(w_proj, wph, wpl, 512);
  qkv_gemm<<<dim3(12, 136), 256, 0, stream>>>(xh, xl, wqh, wql, qh, ql, kh, kl, vt);
  freq_kernel<<<544, 256, 0, stream>>>(qh, ql, kh, kl, af);
  attn_kernel<<<544, 256, 0, stream>>>(qh, kh, vt, af, att_map, weight, fgate,
                                       out_perm);
  proj_gemm<<<dim3(4, 136), 256, 0, stream>>>(out_perm, wph, wpl, b_proj, out);
}

// Round 14
// 409.313 us; speedup vs baseline: 2.0777x; 2.0777x over previous
//
#include <hip/hip_runtime.h>
#include <hip/hip_bf16.h>

// FrequencyAwareSumAttention — round 14: recover from r13's launch-bounds spill.
// attn = round-12 structure exactly (__launch_bounds__(256), 256 VGPR, no spill,
// 170us proven) with ONE improvement kept from r13: K1 writes vT[head][d][t], so
// the Vt LDS stage becomes conflict-free u16x8 copies (kills the 5.19M bank
// conflicts from r12's scalar transpose staging). K0/K2/K4 unchanged.

#define SCALE 0.125f
#define LSTR 72

typedef __attribute__((ext_vector_type(4))) float f32x4;
typedef __attribute__((ext_vector_type(8))) short bf16x8;
typedef __attribute__((ext_vector_type(8))) unsigned short u16x8;

__device__ __forceinline__ float bf2f(unsigned short u) {
  return __uint_as_float(((unsigned int)u) << 16);
}
__device__ __forceinline__ unsigned short f2bf(float f) {
  unsigned int u = __float_as_uint(f);
  u += 0x7FFFu + ((u >> 16) & 1u);
  return (unsigned short)(u >> 16);
}

// ---------------- K0a: x fp32 -> hi/lo bf16 planes ----------------
__global__ __launch_bounds__(256) void conv_x(
    const float* __restrict__ x, unsigned short* __restrict__ xh,
    unsigned short* __restrict__ xl) {
  const size_t i = ((size_t)blockIdx.x * 256 + threadIdx.x) * 8;
  float4 a = *(const float4*)(x + i);
  float4 b = *(const float4*)(x + i + 4);
  float vv[8] = {a.x, a.y, a.z, a.w, b.x, b.y, b.z, b.w};
  u16x8 hi, lo;
#pragma unroll
  for (int e = 0; e < 8; ++e) {
    unsigned short h = f2bf(vv[e]);
    hi[e] = h;
    lo[e] = f2bf(vv[e] - bf2f(h));
  }
  *(u16x8*)&xh[i] = hi;
  *(u16x8*)&xl[i] = lo;
}

// ---------------- K0b: w [K=512][N] -> transposed [N][512] hi/lo planes ----------
__global__ __launch_bounds__(256) void conv_wT(
    const float* __restrict__ w, unsigned short* __restrict__ th,
    unsigned short* __restrict__ tl, int N) {
  __shared__ float T[64][65];
  const int tid = threadIdx.x;
  const int nt = blockIdx.x * 64, kt = blockIdx.y * 64;
  for (int i = tid; i < 4096; i += 256) {
    const int r = i >> 6, c = i & 63;
    T[r][c] = w[(size_t)(kt + r) * N + nt + c];
  }
  __syncthreads();
  for (int i = tid; i < 4096; i += 256) {
    const int rn = i >> 6, ck = i & 63;
    const float v = T[ck][rn];
    const unsigned short h = f2bf(v);
    const size_t o = (size_t)(nt + rn) * 512 + kt + ck;
    th[o] = h;
    tl[o] = f2bf(v - bf2f(h));
  }
}

// ---------------- K1: qkv = x @ w_qkv (split-bf16 MFMA) -> bf16 planes ----------
// q/k: [head][t][d] hi+lo planes.  v: TRANSPOSED [head][d][t] hi plane.
__global__ __launch_bounds__(256, 2) void qkv_gemm(
    const unsigned short* __restrict__ xh, const unsigned short* __restrict__ xl,
    const unsigned short* __restrict__ wh, const unsigned short* __restrict__ wl,
    unsigned short* __restrict__ qh, unsigned short* __restrict__ ql,
    unsigned short* __restrict__ kh, unsigned short* __restrict__ kl,
    unsigned short* __restrict__ vt) {
  __shared__ __attribute__((aligned(16))) unsigned short Wt[2][128 * LSTR];
  __shared__ __attribute__((aligned(16))) unsigned short Xt[2][128 * LSTR];

  const int tid = threadIdx.x;
  const int bx = blockIdx.x, by = blockIdx.y;
  const int wid = tid >> 6, lane = tid & 63;
  const int lr = lane & 15, lg = lane >> 4;
  const int wr = wid >> 1, wc = wid & 1;
  const int srow = tid >> 3, skg = tid & 7;

  const unsigned short* xhp = xh + (size_t)(by * 128 + srow) * 512 + skg * 8;
  const unsigned short* xlp = xl + (size_t)(by * 128 + srow) * 512 + skg * 8;
  const unsigned short* whp = wh + (size_t)(bx * 128 + srow) * 512 + skg * 8;
  const unsigned short* wlp = wl + (size_t)(bx * 128 + srow) * 512 + skg * 8;

  u16x8 rxh[4], rxl[4], rwh[4], rwl[4];
  auto loadk = [&](int k0) {
#pragma unroll
    for (int it = 0; it < 4; ++it) {
      const size_t o = (size_t)(32 * it) * 512 + k0;
      rxh[it] = *(const u16x8*)(xhp + o);
      rxl[it] = *(const u16x8*)(xlp + o);
      rwh[it] = *(const u16x8*)(whp + o);
      rwl[it] = *(const u16x8*)(wlp + o);
    }
  };

  f32x4 acc[4][4];
#pragma unroll
  for (int nt = 0; nt < 4; ++nt)
#pragma unroll
    for (int mt = 0; mt < 4; ++mt) acc[nt][mt] = (f32x4){0.f, 0.f, 0.f, 0.f};

  loadk(0);
  for (int s = 0; s < 8; ++s) {
    if (s) __syncthreads();
#pragma unroll
    for (int it = 0; it < 4; ++it) {
      const int base = (srow + 32 * it) * LSTR + skg * 8;
      *(u16x8*)&Xt[0][base] = rxh[it];
      *(u16x8*)&Xt[1][base] = rxl[it];
      *(u16x8*)&Wt[0][base] = rwh[it];
      *(u16x8*)&Wt[1][base] = rwl[it];
    }
    __syncthreads();
    if (s < 7) loadk((s + 1) * 64);
#pragma unroll
    for (int kh2 = 0; kh2 < 2; ++kh2) {
      const int kbase = kh2 * 32 + lg * 8;
      bf16x8 Ah[4], Al[4], Bh[4], Bl[4];
#pragma unroll
      for (int nt = 0; nt < 4; ++nt) {
        const int n = wr * 64 + nt * 16 + lr;
        Ah[nt] = *(bf16x8*)&Wt[0][n * LSTR + kbase];
        Al[nt] = *(bf16x8*)&Wt[1][n * LSTR + kbase];
      }
#pragma unroll
      for (int mt = 0; mt < 4; ++mt) {
        const int m = wc * 64 + mt * 16 + lr;
        Bh[mt] = *(bf16x8*)&Xt[0][m * LSTR + kbase];
        Bl[mt] = *(bf16x8*)&Xt[1][m * LSTR + kbase];
      }
#pragma unroll
      for (int nt = 0; nt < 4; ++nt)
#pragma unroll
        for (int mt = 0; mt < 4; ++mt) {
          acc[nt][mt] = __builtin_amdgcn_mfma_f32_16x16x32_bf16(Ah[nt], Bh[mt], acc[nt][mt], 0, 0, 0);
          acc[nt][mt] = __builtin_amdgcn_mfma_f32_16x16x32_bf16(Ah[nt], Bl[mt], acc[nt][mt], 0, 0, 0);
          acc[nt][mt] = __builtin_amdgcn_mfma_f32_16x16x32_bf16(Al[nt], Bh[mt], acc[nt][mt], 0, 0, 0);
        }
    }
  }

#pragma unroll
  for (int mt = 0; mt < 4; ++mt) {
    const int m = by * 128 + wc * 64 + mt * 16 + lr;
    const int jj = m % 17;
    const int bt = m / 17;
    const int t = bt & 255;
    const int b = bt >> 8;
#pragma unroll
    for (int nt = 0; nt < 4; ++nt) {
      const int c = bx * 128 + wr * 64 + nt * 16 + lg * 4;
      const int qi = c >> 9;
      const int h = (c >> 6) & 7;
      const int dd = c & 63;
      const size_t hdbase = ((size_t)((b * 8 + h) * 17 + jj)) * 16384;
      float a0 = acc[nt][mt][0], a1 = acc[nt][mt][1], a2 = acc[nt][mt][2],
            a3 = acc[nt][mt][3];
      ushort4 hi4 = make_ushort4(f2bf(a0), f2bf(a1), f2bf(a2), f2bf(a3));
      if (qi == 2) {
        vt[hdbase + (size_t)(dd + 0) * 256 + t] = hi4.x;
        vt[hdbase + (size_t)(dd + 1) * 256 + t] = hi4.y;
        vt[hdbase + (size_t)(dd + 2) * 256 + t] = hi4.z;
        vt[hdbase + (size_t)(dd + 3) * 256 + t] = hi4.w;
      } else {
        ushort4 lo4 = make_ushort4(f2bf(a0 - bf2f(hi4.x)), f2bf(a1 - bf2f(hi4.y)),
                                   f2bf(a2 - bf2f(hi4.z)), f2bf(a3 - bf2f(hi4.w)));
        unsigned short* dh = qi ? kh : qh;
        unsigned short* dl = qi ? kl : ql;
        *(ushort4*)&dh[hdbase + t * 64 + dd] = hi4;
        *(ushort4*)&dl[hdbase + t * 64 + dd] = lo4;
      }
    }
  }
}

// ---------------- K2: MFMA DFT from bf16 planes + af GEMM + softmax -> af bf16 ----
__global__ __launch_bounds__(256) void freq_kernel(
    const unsigned short* __restrict__ qhp, const unsigned short* __restrict__ qlp,
    const unsigned short* __restrict__ khp, const unsigned short* __restrict__ klp,
    unsigned short* __restrict__ af_out) {
  __shared__ __attribute__((aligned(16))) unsigned short qT[2][64 * 256];
  __shared__ __attribute__((aligned(16))) unsigned short QF[4][64 * 64];
  __shared__ __attribute__((aligned(16))) unsigned short KF[4][64 * 64];

  const int tid = threadIdx.x;
  const int head = blockIdx.x;
  const int w = tid >> 6, lane = tid & 63;
  const int lr = lane & 15, lg = lane >> 4;
  const int f0 = w << 4;

  bf16x8 Ech[8], Ecl[8], Esh[8], Esl[8];
  {
    const int f = f0 + lr;
#pragma unroll
    for (int kb = 0; kb < 8; ++kb) {
      bf16x8 ch, cl, sh, sl;
#pragma unroll
      for (int i = 0; i < 8; ++i) {
        int t = kb * 32 + lg * 8 + i;
        int idx = (f * t) & 255;
        float s, c;
        __sincosf((float)idx * 0.02454369260617026f, &s, &c);
        unsigned short chh = f2bf(c);
        unsigned short shh = f2bf(s);
        ch[i] = (short)chh;
        cl[i] = (short)f2bf(c - bf2f(chh));
        sh[i] = (short)shh;
        sl[i] = (short)f2bf(s - bf2f(shh));
      }
      Ech[kb] = ch; Ecl[kb] = cl; Esh[kb] = sh; Esl[kb] = sl;
    }
  }

  for (int pass = 0; pass < 2; ++pass) {
    const unsigned short* sh_ = (pass ? khp : qhp) + head * 16384;
    const unsigned short* sl_ = (pass ? klp : qlp) + head * 16384;
    __syncthreads();
    for (int i = tid; i < 4096; i += 256) {
      int t = i >> 4, dq = i & 15;
      ushort4 hv = *(const ushort4*)&sh_[t * 64 + dq * 4];
      ushort4 lv = *(const ushort4*)&sl_[t * 64 + dq * 4];
      unsigned short hvv[4] = {hv.x, hv.y, hv.z, hv.w};
      unsigned short lvv[4] = {lv.x, lv.y, lv.z, lv.w};
#pragma unroll
      for (int c = 0; c < 4; ++c) {
        int d = dq * 4 + c;
        int byo = d * 512 + ((t * 2) ^ ((d & 31) << 4));
        *(unsigned short*)((char*)qT[0] + byo) = hvv[c];
        *(unsigned short*)((char*)qT[1] + byo) = lvv[c];
      }
    }
    __syncthreads();

    f32x4 ar[4], ai[4];
#pragma unroll
    for (int nt = 0; nt < 4; ++nt) {
      ar[nt] = (f32x4){0.f, 0.f, 0.f, 0.f};
      ai[nt] = (f32x4){0.f, 0.f, 0.f, 0.f};
    }
#pragma unroll
    for (int kb = 0; kb < 8; ++kb) {
#pragma unroll
      for (int nt = 0; nt < 4; ++nt) {
        const int d = nt * 16 + lr;
        const int byo = d * 512 + ((kb * 64 + lg * 16) ^ ((d & 31) << 4));
        bf16x8 bh = *(bf16x8*)((char*)qT[0] + byo);
        bf16x8 bl = *(bf16x8*)((char*)qT[1] + byo);
        ar[nt] = __builtin_amdgcn_mfma_f32_16x16x32_bf16(Ech[kb], bh, ar[nt], 0, 0, 0);
        ar[nt] = __builtin_amdgcn_mfma_f32_16x16x32_bf16(Ech[kb], bl, ar[nt], 0, 0, 0);
        ar[nt] = __builtin_amdgcn_mfma_f32_16x16x32_bf16(Ecl[kb], bh, ar[nt], 0, 0, 0);
        ai[nt] = __builtin_amdgcn_mfma_f32_16x16x32_bf16(Esh[kb], bh, ai[nt], 0, 0, 0);
        ai[nt] = __builtin_amdgcn_mfma_f32_16x16x32_bf16(Esh[kb], bl, ai[nt], 0, 0, 0);
        ai[nt] = __builtin_amdgcn_mfma_f32_16x16x32_bf16(Esl[kb], bh, ai[nt], 0, 0, 0);
      }
    }
    unsigned short(*DST)[64 * 64] = pass ? KF : QF;
#pragma unroll
    for (int nt = 0; nt < 4; ++nt) {
#pragma unroll
      for (int j = 0; j < 4; ++j) {
        const int f = f0 + lg * 4 + j;
        const int d = nt * 16 + lr;
        const int byo = f * 128 + ((d * 2) ^ ((f & 7) << 4));
        float vr = ar[nt][j], vi = ai[nt][j];
        unsigned short rh = f2bf(vr);
        unsigned short ih = f2bf(vi);
        *(unsigned short*)((char*)DST[0] + byo) = rh;
        *(unsigned short*)((char*)DST[1] + byo) = f2bf(vr - bf2f(rh));
        *(unsigned short*)((char*)DST[2] + byo) = ih;
        *(unsigned short*)((char*)DST[3] + byo) = f2bf(vi - bf2f(ih));
      }
    }
  }
  __syncthreads();

  f32x4 acc[4];
#pragma unroll
  for (int nt = 0; nt < 4; ++nt) acc[nt] = (f32x4){0.f, 0.f, 0.f, 0.f};
#pragma unroll
  for (int kb = 0; kb < 2; ++kb) {
    const int fA = f0 + lr;
    const int abyo = fA * 128 + ((kb * 64 + lg * 16) ^ ((fA & 7) << 4));
    bf16x8 arh = *(bf16x8*)((char*)QF[0] + abyo);
    bf16x8 arl = *(bf16x8*)((char*)QF[1] + abyo);
    bf16x8 aih = *(bf16x8*)((char*)QF[2] + abyo);
    bf16x8 ail = *(bf16x8*)((char*)QF[3] + abyo);
#pragma unroll
    for (int nt = 0; nt < 4; ++nt) {
      const int g = nt * 16 + lr;
      const int bbyo = g * 128 + ((kb * 64 + lg * 16) ^ ((g & 7) << 4));
      bf16x8 brh = *(bf16x8*)((char*)KF[0] + bbyo);
      bf16x8 brl = *(bf16x8*)((char*)KF[1] + bbyo);
      bf16x8 bih = *(bf16x8*)((char*)KF[2] + bbyo);
      bf16x8 bil = *(bf16x8*)((char*)KF[3] + bbyo);
      acc[nt] = __builtin_amdgcn_mfma_f32_16x16x32_bf16(arh, brh, acc[nt], 0, 0, 0);
      acc[nt] = __builtin_amdgcn_mfma_f32_16x16x32_bf16(arh, brl, acc[nt], 0, 0, 0);
      acc[nt] = __builtin_amdgcn_mfma_f32_16x16x32_bf16(arl, brh, acc[nt], 0, 0, 0);
      acc[nt] = __builtin_amdgcn_mfma_f32_16x16x32_bf16(aih, bih, acc[nt], 0, 0, 0);
      acc[nt] = __builtin_amdgcn_mfma_f32_16x16x32_bf16(aih, bil, acc[nt], 0, 0, 0);
      acc[nt] = __builtin_amdgcn_mfma_f32_16x16x32_bf16(ail, bih, acc[nt], 0, 0, 0);
    }
  }

  unsigned short* outh = af_out + head * 4096;
#pragma unroll
  for (int j = 0; j < 4; ++j) {
    float m = fmaxf(fmaxf(acc[0][j], acc[1][j]), fmaxf(acc[2][j], acc[3][j]));
#pragma unroll
    for (int mask = 1; mask < 16; mask <<= 1) m = fmaxf(m, __shfl_xor(m, mask));
    float e[4];
    float rs = 0.f;
#pragma unroll
    for (int nt = 0; nt < 4; ++nt) {
      e[nt] = __expf((acc[nt][j] - m) * SCALE);
      rs += e[nt];
    }
#pragma unroll
    for (int mask = 1; mask < 16; mask <<= 1) rs += __shfl_xor(rs, mask);
    const float inv = 1.0f / rs;
    const int f = f0 + lg * 4 + j;
#pragma unroll
    for (int nt = 0; nt < 4; ++nt) outh[f * 64 + nt * 16 + lr] = f2bf(e[nt] * inv);
  }
}

// ---------------- K3: round-12 merged MFMA attention, Vt staged by copy ----------
__global__ __launch_bounds__(256) void attn_kernel(
    const unsigned short* __restrict__ qhp, const unsigned short* __restrict__ khp,
    const unsigned short* __restrict__ vtp, const unsigned short* __restrict__ af,
    const float* __restrict__ att_map, const float* __restrict__ weight,
    const float* __restrict__ fgate, float* __restrict__ out_perm) {
  __shared__ unsigned short Ks[256 * 64];
  __shared__ unsigned short Vt[64 * 256];
  __shared__ unsigned short afl[64 * 66];
  __shared__ unsigned short Psc[4][16 * 40];

  const int tid = threadIdx.x;
  const int head = blockIdx.x;
  const int jj = head % 17;
  const int hb = head / 17;
  const int h = hb & 7;
  const int b = hb >> 3;
  const int w = tid >> 6, lane = tid & 63;
  const int lr = lane & 15, lg = lane >> 4;

  const float* amh = att_map + (size_t)head * 65536;
  const unsigned short* qbase = qhp + head * 16384;

  // ---- issue tile-0 Q frag loads early ----
  bf16x8 rq[2];
  {
    const unsigned short* qrow = qbase + (w * 64 + lr) * 64 + lg * 8;
    rq[0] = *(const bf16x8*)(qrow);
    rq[1] = *(const bf16x8*)(qrow + 32);
  }

  // ---- stage K and Vt (both 16B-granule swizzle COPIES — conflict-free) ----
  const unsigned short* ksrc = khp + head * 16384;
  const unsigned short* vsrc = vtp + head * 16384;  // vT[d][t]
  for (int i = tid; i < 2048; i += 256) {
    int s = i >> 3, dq8 = i & 7;
    u16x8 kv = *(const u16x8*)&ksrc[s * 64 + dq8 * 8];
    int koff = s * 128 + ((dq8 * 16) ^ ((s & 7) << 4));
    *(u16x8*)((char*)Ks + koff) = kv;
    // Vt[d][t]: i -> d = i>>5, t8 = i&31 (8-elem granule along t)
    int d = i >> 5, t8 = i & 31;
    u16x8 vv = *(const u16x8*)&vsrc[d * 256 + t8 * 8];
    int voff = d * 512 + ((t8 * 16) ^ ((d & 7) << 4));
    *(u16x8*)((char*)Vt + voff) = vv;
  }
  const unsigned short* asrc = af + head * 4096;
  for (int i = tid; i < 1024; i += 256) {
    int f = i >> 4, gq = (i & 15) << 2;
    *(ushort4*)&afl[f * 66 + gq] = *(const ushort4*)&asrc[f * 64 + gq];
  }
  __syncthreads();

  const float wv = weight[0];
  const float gate = 1.0f / (1.0f + __expf(-fgate[0]));
  unsigned short* psc = Psc[w];

  for (int tt = 0; tt < 4; ++tt) {
    const int tw = w * 64 + tt * 16;

    bf16x8 aq[2] = {rq[0], rq[1]};

    // ---- QK^T ----
    f32x4 S[16];
#pragma unroll
    for (int nt = 0; nt < 16; ++nt) {
      f32x4 accv = {0.f, 0.f, 0.f, 0.f};
#pragma unroll
      for (int kc = 0; kc < 2; ++kc) {
        int srow = nt * 16 + lr;
        int d0 = kc * 32 + lg * 8;
        int off = srow * 128 + ((d0 * 2) ^ ((srow & 7) << 4));
        bf16x8 bk = *(bf16x8*)((char*)Ks + off);
        accv = __builtin_amdgcn_mfma_f32_16x16x32_bf16(aq[kc], bk, accv, 0, 0, 0);
      }
      S[nt] = accv;
    }

    // ---- prefetch next tile's Q ----
    if (tt < 3) {
      const unsigned short* qrow = qbase + (tw + 16 + lr) * 64 + lg * 8;
      rq[0] = *(const bf16x8*)(qrow);
      rq[1] = *(const bf16x8*)(qrow + 32);
    }

    // ---- softmax (16-lane xor groups) ----
    float inv[4], mrow[4];
#pragma unroll
    for (int j = 0; j < 4; ++j) {
      float m = -1e30f;
#pragma unroll
      for (int nt = 0; nt < 16; ++nt) m = fmaxf(m, S[nt][j]);
#pragma unroll
      for (int mask = 1; mask < 16; mask <<= 1) m = fmaxf(m, __shfl_xor(m, mask));
      mrow[j] = m;
    }
#pragma unroll
    for (int j = 0; j < 4; ++j) {
      float rs = 0.f;
#pragma unroll
      for (int nt = 0; nt < 16; ++nt) {
        float e = __expf((S[nt][j] - mrow[j]) * SCALE);
        S[nt][j] = e;
        rs += e;
      }
#pragma unroll
      for (int mask = 1; mask < 16; mask <<= 1) rs += __shfl_xor(rs, mask);
      inv[j] = 1.0f / rs;
    }

    // ---- combine: interp(freq) + att_map + time softmax ----
#pragma unroll
    for (int j = 0; j < 4; ++j) {
      const int t = tw + lg * 4 + j;
      float srcf = fmaxf((t + 0.5f) * (129.0f / 256.0f) - 0.5f, 0.0f);
      int f0r = (int)srcf;
      float wf = srcf - (float)f0r;
      int f1r = f0r + 1;
      if (f1r > 128) f1r = 128;
      const bool v0 = (f0r < 64), v1 = (f1r < 64);
#pragma unroll
      for (int nt = 0; nt < 16; ++nt) {
        const int s = nt * 16 + lr;
        float am = amh[t * 256 + s];
        float srcg = fmaxf((s + 0.5f) * 0.25f - 0.5f, 0.0f);
        int g0 = (int)srcg;
        float wc = srcg - (float)g0;
        int g1 = g0 + 1;
        if (g1 > 63) g1 = 63;
        float fr = 0.f;
        if (v0)
          fr += (1.0f - wf) *
                (bf2f(afl[f0r * 66 + g0]) * (1.0f - wc) + bf2f(afl[f0r * 66 + g1]) * wc);
        if (v1)
          fr += wf *
                (bf2f(afl[f1r * 66 + g0]) * (1.0f - wc) + bf2f(afl[f1r * 66 + g1]) * wc);
        float pt = S[nt][j] * inv[j];
        S[nt][j] = wv * (gate * fr + (1.0f - gate) * pt) + (1.0f - wv) * am;
      }
    }

    // ---- PV ----
    f32x4 O[4];
#pragma unroll
    for (int dt = 0; dt < 4; ++dt) O[dt] = (f32x4){0.f, 0.f, 0.f, 0.f};
#pragma unroll
    for (int sb = 0; sb < 8; ++sb) {
#pragma unroll
      for (int half = 0; half < 2; ++half) {
        const int nt = sb * 2 + half;
#pragma unroll
        for (int j = 0; j < 4; ++j) {
          psc[(lg * 4 + j) * 40 + half * 16 + lr] = f2bf(S[nt][j]);
        }
      }
      bf16x8 pa = *(bf16x8*)&psc[lr * 40 + lg * 8];
      const int s0 = sb * 32 + lg * 8;
#pragma unroll
      for (int dt = 0; dt < 4; ++dt) {
        const int d = dt * 16 + lr;
        // Vt LDS [d][t] with 16B-granule swizzle: t8 = s0/8
        int off = d * 512 + ((s0 * 2) ^ ((d & 7) << 4));
        bf16x8 bv = *(bf16x8*)((char*)Vt + off);
        O[dt] = __builtin_amdgcn_mfma_f32_16x16x32_bf16(pa, bv, O[dt], 0, 0, 0);
      }
    }

    // ---- write out_perm ----
#pragma unroll
    for (int j = 0; j < 4; ++j) {
      const int t = tw + lg * 4 + j;
      float* orow = out_perm + ((size_t)((b * 256 + t) * 17 + jj)) * 512 + h * 64;
#pragma unroll
      for (int dt = 0; dt < 4; ++dt) {
        orow[dt * 16 + lr] = O[dt][j];
      }
    }
  }
}

// ---------------- K4: d_out = out_perm @ w_proj + b_proj (split-bf16 MFMA) --------
__global__ __launch_bounds__(256, 2) void proj_gemm(
    const float* __restrict__ A,
    const unsigned short* __restrict__ wh, const unsigned short* __restrict__ wl,
    const float* __restrict__ bias, float* __restrict__ out) {
  __shared__ __attribute__((aligned(16))) unsigned short Wt[2][128 * LSTR];
  __shared__ __attribute__((aligned(16))) unsigned short Xt[2][128 * LSTR];

  const int tid = threadIdx.x;
  const int bx = blockIdx.x, by = blockIdx.y;
  const int wid = tid >> 6, lane = tid & 63;
  const int lr = lane & 15, lg = lane >> 4;
  const int wr = wid >> 1, wc = wid & 1;
  const int srow = tid >> 3, skg = tid & 7;

  const float* ap = A + (size_t)(by * 128 + srow) * 512 + skg * 8;
  const unsigned short* whp = wh + (size_t)(bx * 128 + srow) * 512 + skg * 8;
  const unsigned short* wlp = wl + (size_t)(bx * 128 + srow) * 512 + skg * 8;

  float4 rA[4][2];
  u16x8 rwh[4], rwl[4];
  auto loadk = [&](int k0) {
#pragma unroll
    for (int it = 0; it < 4; ++it) {
      const size_t o = (size_t)(32 * it) * 512 + k0;
      rA[it][0] = *(const float4*)(ap + o);
      rA[it][1] = *(const float4*)(ap + o + 4);
      rwh[it] = *(const u16x8*)(whp + o);
      rwl[it] = *(const u16x8*)(wlp + o);
    }
  };

  f32x4 acc[4][4];
#pragma unroll
  for (int nt = 0; nt < 4; ++nt)
#pragma unroll
    for (int mt = 0; mt < 4; ++mt) acc[nt][mt] = (f32x4){0.f, 0.f, 0.f, 0.f};

  loadk(0);
  for (int s = 0; s < 8; ++s) {
    if (s) __syncthreads();
#pragma unroll
    for (int it = 0; it < 4; ++it) {
      const int base = (srow + 32 * it) * LSTR + skg * 8;
      float vv[8] = {rA[it][0].x, rA[it][0].y, rA[it][0].z, rA[it][0].w,
                     rA[it][1].x, rA[it][1].y, rA[it][1].z, rA[it][1].w};
      u16x8 hi, lo;
#pragma unroll
      for (int e = 0; e < 8; ++e) {
        unsigned short h = f2bf(vv[e]);
        hi[e] = h;
        lo[e] = f2bf(vv[e] - bf2f(h));
      }
      *(u16x8*)&Xt[0][base] = hi;
      *(u16x8*)&Xt[1][base] = lo;
      *(u16x8*)&Wt[0][base] = rwh[it];
      *(u16x8*)&Wt[1][base] = rwl[it];
    }
    __syncthreads();
    if (s < 7) loadk((s + 1) * 64);
#pragma unroll
    for (int kh2 = 0; kh2 < 2; ++kh2) {
      const int kbase = kh2 * 32 + lg * 8;
      bf16x8 Ah[4], Al[4], Bh[4], Bl[4];
#pragma unroll
      for (int nt = 0; nt < 4; ++nt) {
        const int n = wr * 64 + nt * 16 + lr;
        Ah[nt] = *(bf16x8*)&Wt[0][n * LSTR + kbase];
        Al[nt] = *(bf16x8*)&Wt[1][n * LSTR + kbase];
      }
#pragma unroll
      for (int mt = 0; mt < 4; ++mt) {
        const int m = wc * 64 + mt * 16 + lr;
        Bh[mt] = *(bf16x8*)&Xt[0][m * LSTR + kbase];
        Bl[mt] = *(bf16x8*)&Xt[1][m * LSTR + kbase];
      }
#pragma unroll
      for (int nt = 0; nt < 4; ++nt)
#pragma unroll
        for (int mt = 0; mt < 4; ++mt) {
          acc[nt][mt] = __builtin_amdgcn_mfma_f32_16x16x32_bf16(Ah[nt], Bh[mt], acc[nt][mt], 0, 0, 0);
          acc[nt][mt] = __builtin_amdgcn_mfma_f32_16x16x32_bf16(Ah[nt], Bl[mt], acc[nt][mt], 0, 0, 0);
          acc[nt][mt] = __builtin_amdgcn_mfma_f32_16x16x32_bf16(Al[nt], Bh[mt], acc[nt][mt], 0, 0, 0);
        }
    }
  }

#pragma unroll
  for (int mt = 0; mt < 4; ++mt) {
    const int m = by * 128 + wc * 64 + mt * 16 + lr;
#pragma unroll
    for (int nt = 0; nt < 4; ++nt) {
      const int n = bx * 128 + wr * 64 + nt * 16 + lg * 4;
      float4 bi = *(const float4*)&bias[n];
      *(float4*)&out[(size_t)m * 512 + n] =
          make_float4(acc[nt][mt][0] + bi.x, acc[nt][mt][1] + bi.y,
                      acc[nt][mt][2] + bi.z, acc[nt][mt][3] + bi.w);
    }
  }
}

extern "C" void kernel_launch(void* const* d_in, const int* in_sizes, int n_in,
                              void* d_out, int out_size, void* d_ws, size_t ws_size,
                              hipStream_t stream) {
  (void)in_sizes; (void)n_in; (void)out_size; (void)ws_size;
  const float* x = (const float*)d_in[0];
  const float* att_map = (const float*)d_in[1];
  const float* weight = (const float*)d_in[2];
  const float* w_qkv = (const float*)d_in[3];
  const float* w_proj = (const float*)d_in[4];
  const float* b_proj = (const float*)d_in[5];
  const float* fgate = (const float*)d_in[6];
  float* out = (float*)d_out;

  char* ws = (char*)d_ws;
  const size_t PB = 17825792;  // one bf16 plane: 544*16384*2 B
  unsigned short* qh = (unsigned short*)(ws);
  unsigned short* ql = (unsigned short*)(ws + PB);
  unsigned short* kh = (unsigned short*)(ws + 2 * PB);
  unsigned short* kl = (unsigned short*)(ws + 3 * PB);
  unsigned short* vt = (unsigned short*)(ws + 4 * PB);
  unsigned short* af = (unsigned short*)(ws + 5 * PB);  // 544*4096 bf16
  char* base = ws + 5 * PB + 4456448;
  unsigned short* xh = (unsigned short*)(base);
  unsigned short* xl = (unsigned short*)(base + PB);
  float* out_perm = (float*)(base);  // alias xh/xl (disjoint lifetimes)
  unsigned short* wqh = (unsigned short*)(base + 35651584);
  unsigned short* wql = (unsigned short*)(base + 35651584 + 1572864);
  unsigned short* wph = (unsigned short*)(base + 35651584 + 2 * 1572864);
  unsigned short* wpl = (unsigned short*)(base + 35651584 + 2 * 1572864 + 524288);

  conv_x<<<4352, 256, 0, stream>>>(x, xh, xl);
  conv_wT<<<dim3(24, 8), 256, 0, stream>>>(w_qkv, wqh, wql, 1536);
  conv_wT<<<dim3(8, 8), 256, 0, stream>>>(w_proj, wph, wpl, 512);
  qkv_gemm<<<dim3(12, 136), 256, 0, stream>>>(xh, xl, wqh, wql, qh, ql, kh, kl, vt);
  freq_kernel<<<544, 256, 0, stream>>>(qh, ql, kh, kl, af);
  attn_kernel<<<544, 256, 0, stream>>>(qh, kh, vt, af, att_map, weight, fgate,
                                       out_perm);
  proj_gemm<<<dim3(4, 136), 256, 0, stream>>>(out_perm, wph, wpl, b_proj, out);
}

// Round 15
// 379.127 us; speedup vs baseline: 2.2431x; 1.0796x over previous
//
#include <hip/hip_runtime.h>
#include <hip/hip_bf16.h>

// FrequencyAwareSumAttention — round 15: kill attn's combine loop algebraically.
// freq term is linear in V: precompute Wf = AF256 @ V (MFMA prologue, Wf bf16
// overwrites dead afl buffer; LDS unchanged -> 2 blocks/CU), then per t-row just
// 2 Wf reads + fma. am folds into the P A-frag (s is fast axis -> float4 loads,
// 1-deep pipelined). Combine loop (900 LDS + 2500 VALU + 64 scalar glob loads
// per thread per tile) deleted. K0/K1/K2/K4 identical to round 14.

#define SCALE 0.125f
#define LSTR 72

typedef __attribute__((ext_vector_type(4))) float f32x4;
typedef __attribute__((ext_vector_type(8))) short bf16x8;
typedef __attribute__((ext_vector_type(8))) unsigned short u16x8;

__device__ __forceinline__ float bf2f(unsigned short u) {
  return __uint_as_float(((unsigned int)u) << 16);
}
__device__ __forceinline__ unsigned short f2bf(float f) {
  unsigned int u = __float_as_uint(f);
  u += 0x7FFFu + ((u >> 16) & 1u);
  return (unsigned short)(u >> 16);
}

// ---------------- K0a: x fp32 -> hi/lo bf16 planes ----------------
__global__ __launch_bounds__(256) void conv_x(
    const float* __restrict__ x, unsigned short* __restrict__ xh,
    unsigned short* __restrict__ xl) {
  const size_t i = ((size_t)blockIdx.x * 256 + threadIdx.x) * 8;
  float4 a = *(const float4*)(x + i);
  float4 b = *(const float4*)(x + i + 4);
  float vv[8] = {a.x, a.y, a.z, a.w, b.x, b.y, b.z, b.w};
  u16x8 hi, lo;
#pragma unroll
  for (int e = 0; e < 8; ++e) {
    unsigned short h = f2bf(vv[e]);
    hi[e] = h;
    lo[e] = f2bf(vv[e] - bf2f(h));
  }
  *(u16x8*)&xh[i] = hi;
  *(u16x8*)&xl[i] = lo;
}

// ---------------- K0b: w [K=512][N] -> transposed [N][512] hi/lo planes ----------
__global__ __launch_bounds__(256) void conv_wT(
    const float* __restrict__ w, unsigned short* __restrict__ th,
    unsigned short* __restrict__ tl, int N) {
  __shared__ float T[64][65];
  const int tid = threadIdx.x;
  const int nt = blockIdx.x * 64, kt = blockIdx.y * 64;
  for (int i = tid; i < 4096; i += 256) {
    const int r = i >> 6, c = i & 63;
    T[r][c] = w[(size_t)(kt + r) * N + nt + c];
  }
  __syncthreads();
  for (int i = tid; i < 4096; i += 256) {
    const int rn = i >> 6, ck = i & 63;
    const float v = T[ck][rn];
    const unsigned short h = f2bf(v);
    const size_t o = (size_t)(nt + rn) * 512 + kt + ck;
    th[o] = h;
    tl[o] = f2bf(v - bf2f(h));
  }
}

// ---------------- K1: qkv = x @ w_qkv (split-bf16 MFMA) -> bf16 planes ----------
__global__ __launch_bounds__(256, 2) void qkv_gemm(
    const unsigned short* __restrict__ xh, const unsigned short* __restrict__ xl,
    const unsigned short* __restrict__ wh, const unsigned short* __restrict__ wl,
    unsigned short* __restrict__ qh, unsigned short* __restrict__ ql,
    unsigned short* __restrict__ kh, unsigned short* __restrict__ kl,
    unsigned short* __restrict__ vt) {
  __shared__ __attribute__((aligned(16))) unsigned short Wt[2][128 * LSTR];
  __shared__ __attribute__((aligned(16))) unsigned short Xt[2][128 * LSTR];

  const int tid = threadIdx.x;
  const int bx = blockIdx.x, by = blockIdx.y;
  const int wid = tid >> 6, lane = tid & 63;
  const int lr = lane & 15, lg = lane >> 4;
  const int wr = wid >> 1, wc = wid & 1;
  const int srow = tid >> 3, skg = tid & 7;

  const unsigned short* xhp = xh + (size_t)(by * 128 + srow) * 512 + skg * 8;
  const unsigned short* xlp = xl + (size_t)(by * 128 + srow) * 512 + skg * 8;
  const unsigned short* whp = wh + (size_t)(bx * 128 + srow) * 512 + skg * 8;
  const unsigned short* wlp = wl + (size_t)(bx * 128 + srow) * 512 + skg * 8;

  u16x8 rxh[4], rxl[4], rwh[4], rwl[4];
  auto loadk = [&](int k0) {
#pragma unroll
    for (int it = 0; it < 4; ++it) {
      const size_t o = (size_t)(32 * it) * 512 + k0;
      rxh[it] = *(const u16x8*)(xhp + o);
      rxl[it] = *(const u16x8*)(xlp + o);
      rwh[it] = *(const u16x8*)(whp + o);
      rwl[it] = *(const u16x8*)(wlp + o);
    }
  };

  f32x4 acc[4][4];
#pragma unroll
  for (int nt = 0; nt < 4; ++nt)
#pragma unroll
    for (int mt = 0; mt < 4; ++mt) acc[nt][mt] = (f32x4){0.f, 0.f, 0.f, 0.f};

  loadk(0);
  for (int s = 0; s < 8; ++s) {
    if (s) __syncthreads();
#pragma unroll
    for (int it = 0; it < 4; ++it) {
      const int base = (srow + 32 * it) * LSTR + skg * 8;
      *(u16x8*)&Xt[0][base] = rxh[it];
      *(u16x8*)&Xt[1][base] = rxl[it];
      *(u16x8*)&Wt[0][base] = rwh[it];
      *(u16x8*)&Wt[1][base] = rwl[it];
    }
    __syncthreads();
    if (s < 7) loadk((s + 1) * 64);
#pragma unroll
    for (int kh2 = 0; kh2 < 2; ++kh2) {
      const int kbase = kh2 * 32 + lg * 8;
      bf16x8 Ah[4], Al[4], Bh[4], Bl[4];
#pragma unroll
      for (int nt = 0; nt < 4; ++nt) {
        const int n = wr * 64 + nt * 16 + lr;
        Ah[nt] = *(bf16x8*)&Wt[0][n * LSTR + kbase];
        Al[nt] = *(bf16x8*)&Wt[1][n * LSTR + kbase];
      }
#pragma unroll
      for (int mt = 0; mt < 4; ++mt) {
        const int m = wc * 64 + mt * 16 + lr;
        Bh[mt] = *(bf16x8*)&Xt[0][m * LSTR + kbase];
        Bl[mt] = *(bf16x8*)&Xt[1][m * LSTR + kbase];
      }
#pragma unroll
      for (int nt = 0; nt < 4; ++nt)
#pragma unroll
        for (int mt = 0; mt < 4; ++mt) {
          acc[nt][mt] = __builtin_amdgcn_mfma_f32_16x16x32_bf16(Ah[nt], Bh[mt], acc[nt][mt], 0, 0, 0);
          acc[nt][mt] = __builtin_amdgcn_mfma_f32_16x16x32_bf16(Ah[nt], Bl[mt], acc[nt][mt], 0, 0, 0);
          acc[nt][mt] = __builtin_amdgcn_mfma_f32_16x16x32_bf16(Al[nt], Bh[mt], acc[nt][mt], 0, 0, 0);
        }
    }
  }

#pragma unroll
  for (int mt = 0; mt < 4; ++mt) {
    const int m = by * 128 + wc * 64 + mt * 16 + lr;
    const int jj = m % 17;
    const int bt = m / 17;
    const int t = bt & 255;
    const int b = bt >> 8;
#pragma unroll
    for (int nt = 0; nt < 4; ++nt) {
      const int c = bx * 128 + wr * 64 + nt * 16 + lg * 4;
      const int qi = c >> 9;
      const int h = (c >> 6) & 7;
      const int dd = c & 63;
      const size_t hdbase = ((size_t)((b * 8 + h) * 17 + jj)) * 16384;
      float a0 = acc[nt][mt][0], a1 = acc[nt][mt][1], a2 = acc[nt][mt][2],
            a3 = acc[nt][mt][3];
      ushort4 hi4 = make_ushort4(f2bf(a0), f2bf(a1), f2bf(a2), f2bf(a3));
      if (qi == 2) {
        vt[hdbase + (size_t)(dd + 0) * 256 + t] = hi4.x;
        vt[hdbase + (size_t)(dd + 1) * 256 + t] = hi4.y;
        vt[hdbase + (size_t)(dd + 2) * 256 + t] = hi4.z;
        vt[hdbase + (size_t)(dd + 3) * 256 + t] = hi4.w;
      } else {
        ushort4 lo4 = make_ushort4(f2bf(a0 - bf2f(hi4.x)), f2bf(a1 - bf2f(hi4.y)),
                                   f2bf(a2 - bf2f(hi4.z)), f2bf(a3 - bf2f(hi4.w)));
        unsigned short* dh = qi ? kh : qh;
        unsigned short* dl = qi ? kl : ql;
        *(ushort4*)&dh[hdbase + t * 64 + dd] = hi4;
        *(ushort4*)&dl[hdbase + t * 64 + dd] = lo4;
      }
    }
  }
}

// ---------------- K2: MFMA DFT from bf16 planes + af GEMM + softmax -> af bf16 ----
__global__ __launch_bounds__(256) void freq_kernel(
    const unsigned short* __restrict__ qhp, const unsigned short* __restrict__ qlp,
    const unsigned short* __restrict__ khp, const unsigned short* __restrict__ klp,
    unsigned short* __restrict__ af_out) {
  __shared__ __attribute__((aligned(16))) unsigned short qT[2][64 * 256];
  __shared__ __attribute__((aligned(16))) unsigned short QF[4][64 * 64];
  __shared__ __attribute__((aligned(16))) unsigned short KF[4][64 * 64];

  const int tid = threadIdx.x;
  const int head = blockIdx.x;
  const int w = tid >> 6, lane = tid & 63;
  const int lr = lane & 15, lg = lane >> 4;
  const int f0 = w << 4;

  bf16x8 Ech[8], Ecl[8], Esh[8], Esl[8];
  {
    const int f = f0 + lr;
#pragma unroll
    for (int kb = 0; kb < 8; ++kb) {
      bf16x8 ch, cl, sh, sl;
#pragma unroll
      for (int i = 0; i < 8; ++i) {
        int t = kb * 32 + lg * 8 + i;
        int idx = (f * t) & 255;
        float s, c;
        __sincosf((float)idx * 0.02454369260617026f, &s, &c);
        unsigned short chh = f2bf(c);
        unsigned short shh = f2bf(s);
        ch[i] = (short)chh;
        cl[i] = (short)f2bf(c - bf2f(chh));
        sh[i] = (short)shh;
        sl[i] = (short)f2bf(s - bf2f(shh));
      }
      Ech[kb] = ch; Ecl[kb] = cl; Esh[kb] = sh; Esl[kb] = sl;
    }
  }

  for (int pass = 0; pass < 2; ++pass) {
    const unsigned short* sh_ = (pass ? khp : qhp) + head * 16384;
    const unsigned short* sl_ = (pass ? klp : qlp) + head * 16384;
    __syncthreads();
    for (int i = tid; i < 4096; i += 256) {
      int t = i >> 4, dq = i & 15;
      ushort4 hv = *(const ushort4*)&sh_[t * 64 + dq * 4];
      ushort4 lv = *(const ushort4*)&sl_[t * 64 + dq * 4];
      unsigned short hvv[4] = {hv.x, hv.y, hv.z, hv.w};
      unsigned short lvv[4] = {lv.x, lv.y, lv.z, lv.w};
#pragma unroll
      for (int c = 0; c < 4; ++c) {
        int d = dq * 4 + c;
        int byo = d * 512 + ((t * 2) ^ ((d & 31) << 4));
        *(unsigned short*)((char*)qT[0] + byo) = hvv[c];
        *(unsigned short*)((char*)qT[1] + byo) = lvv[c];
      }
    }
    __syncthreads();

    f32x4 ar[4], ai[4];
#pragma unroll
    for (int nt = 0; nt < 4; ++nt) {
      ar[nt] = (f32x4){0.f, 0.f, 0.f, 0.f};
      ai[nt] = (f32x4){0.f, 0.f, 0.f, 0.f};
    }
#pragma unroll
    for (int kb = 0; kb < 8; ++kb) {
#pragma unroll
      for (int nt = 0; nt < 4; ++nt) {
        const int d = nt * 16 + lr;
        const int byo = d * 512 + ((kb * 64 + lg * 16) ^ ((d & 31) << 4));
        bf16x8 bh = *(bf16x8*)((char*)qT[0] + byo);
        bf16x8 bl = *(bf16x8*)((char*)qT[1] + byo);
        ar[nt] = __builtin_amdgcn_mfma_f32_16x16x32_bf16(Ech[kb], bh, ar[nt], 0, 0, 0);
        ar[nt] = __builtin_amdgcn_mfma_f32_16x16x32_bf16(Ech[kb], bl, ar[nt], 0, 0, 0);
        ar[nt] = __builtin_amdgcn_mfma_f32_16x16x32_bf16(Ecl[kb], bh, ar[nt], 0, 0, 0);
        ai[nt] = __builtin_amdgcn_mfma_f32_16x16x32_bf16(Esh[kb], bh, ai[nt], 0, 0, 0);
        ai[nt] = __builtin_amdgcn_mfma_f32_16x16x32_bf16(Esh[kb], bl, ai[nt], 0, 0, 0);
        ai[nt] = __builtin_amdgcn_mfma_f32_16x16x32_bf16(Esl[kb], bh, ai[nt], 0, 0, 0);
      }
    }
    unsigned short(*DST)[64 * 64] = pass ? KF : QF;
#pragma unroll
    for (int nt = 0; nt < 4; ++nt) {
#pragma unroll
      for (int j = 0; j < 4; ++j) {
        const int f = f0 + lg * 4 + j;
        const int d = nt * 16 + lr;
        const int byo = f * 128 + ((d * 2) ^ ((f & 7) << 4));
        float vr = ar[nt][j], vi = ai[nt][j];
        unsigned short rh = f2bf(vr);
        unsigned short ih = f2bf(vi);
        *(unsigned short*)((char*)DST[0] + byo) = rh;
        *(unsigned short*)((char*)DST[1] + byo) = f2bf(vr - bf2f(rh));
        *(unsigned short*)((char*)DST[2] + byo) = ih;
        *(unsigned short*)((char*)DST[3] + byo) = f2bf(vi - bf2f(ih));
      }
    }
  }
  __syncthreads();

  f32x4 acc[4];
#pragma unroll
  for (int nt = 0; nt < 4; ++nt) acc[nt] = (f32x4){0.f, 0.f, 0.f, 0.f};
#pragma unroll
  for (int kb = 0; kb < 2; ++kb) {
    const int fA = f0 + lr;
    const int abyo = fA * 128 + ((kb * 64 + lg * 16) ^ ((fA & 7) << 4));
    bf16x8 arh = *(bf16x8*)((char*)QF[0] + abyo);
    bf16x8 arl = *(bf16x8*)((char*)QF[1] + abyo);
    bf16x8 aih = *(bf16x8*)((char*)QF[2] + abyo);
    bf16x8 ail = *(bf16x8*)((char*)QF[3] + abyo);
#pragma unroll
    for (int nt = 0; nt < 4; ++nt) {
      const int g = nt * 16 + lr;
      const int bbyo = g * 128 + ((kb * 64 + lg * 16) ^ ((g & 7) << 4));
      bf16x8 brh = *(bf16x8*)((char*)KF[0] + bbyo);
      bf16x8 brl = *(bf16x8*)((char*)KF[1] + bbyo);
      bf16x8 bih = *(bf16x8*)((char*)KF[2] + bbyo);
      bf16x8 bil = *(bf16x8*)((char*)KF[3] + bbyo);
      acc[nt] = __builtin_amdgcn_mfma_f32_16x16x32_bf16(arh, brh, acc[nt], 0, 0, 0);
      acc[nt] = __builtin_amdgcn_mfma_f32_16x16x32_bf16(arh, brl, acc[nt], 0, 0, 0);
      acc[nt] = __builtin_amdgcn_mfma_f32_16x16x32_bf16(arl, brh, acc[nt], 0, 0, 0);
      acc[nt] = __builtin_amdgcn_mfma_f32_16x16x32_bf16(aih, bih, acc[nt], 0, 0, 0);
      acc[nt] = __builtin_amdgcn_mfma_f32_16x16x32_bf16(aih, bil, acc[nt], 0, 0, 0);
      acc[nt] = __builtin_amdgcn_mfma_f32_16x16x32_bf16(ail, bih, acc[nt], 0, 0, 0);
    }
  }

  unsigned short* outh = af_out + head * 4096;
#pragma unroll
  for (int j = 0; j < 4; ++j) {
    float m = fmaxf(fmaxf(acc[0][j], acc[1][j]), fmaxf(acc[2][j], acc[3][j]));
#pragma unroll
    for (int mask = 1; mask < 16; mask <<= 1) m = fmaxf(m, __shfl_xor(m, mask));
    float e[4];
    float rs = 0.f;
#pragma unroll
    for (int nt = 0; nt < 4; ++nt) {
      e[nt] = __expf((acc[nt][j] - m) * SCALE);
      rs += e[nt];
    }
#pragma unroll
    for (int mask = 1; mask < 16; mask <<= 1) rs += __shfl_xor(rs, mask);
    const float inv = 1.0f / rs;
    const int f = f0 + lg * 4 + j;
#pragma unroll
    for (int nt = 0; nt < 4; ++nt) outh[f * 64 + nt * 16 + lr] = f2bf(e[nt] * inv);
  }
}

// ---------------- K3: attn with Wf prologue + am-in-A-frag (no combine loop) -----
__global__ __launch_bounds__(256) void attn_kernel(
    const unsigned short* __restrict__ qhp, const unsigned short* __restrict__ khp,
    const unsigned short* __restrict__ vtp, const unsigned short* __restrict__ af,
    const float* __restrict__ att_map, const float* __restrict__ weight,
    const float* __restrict__ fgate, float* __restrict__ out_perm) {
  __shared__ unsigned short Ks[256 * 64];
  __shared__ unsigned short Vt[64 * 256];
  __shared__ unsigned short AFW[64 * 66];  // afl first, then Wf (bf16)
  __shared__ unsigned short Psc[4][16 * 40];

  const int tid = threadIdx.x;
  const int head = blockIdx.x;
  const int jj = head % 17;
  const int hb = head / 17;
  const int h = hb & 7;
  const int b = hb >> 3;
  const int w = tid >> 6, lane = tid & 63;
  const int lr = lane & 15, lg = lane >> 4;

  const float* amh = att_map + (size_t)head * 65536;
  const unsigned short* qbase = qhp + head * 16384;

  // ---- stage K and Vt (16B-granule swizzle copies) and afl ----
  const unsigned short* ksrc = khp + head * 16384;
  const unsigned short* vsrc = vtp + head * 16384;  // vT[d][t]
  for (int i = tid; i < 2048; i += 256) {
    int s = i >> 3, dq8 = i & 7;
    u16x8 kv = *(const u16x8*)&ksrc[s * 64 + dq8 * 8];
    int koff = s * 128 + ((dq8 * 16) ^ ((s & 7) << 4));
    *(u16x8*)((char*)Ks + koff) = kv;
    int d = i >> 5, t8 = i & 31;
    u16x8 vv = *(const u16x8*)&vsrc[d * 256 + t8 * 8];
    int voff = d * 512 + ((t8 * 16) ^ ((d & 7) << 4));
    *(u16x8*)((char*)Vt + voff) = vv;
  }
  const unsigned short* asrc = af + head * 4096;
  for (int i = tid; i < 1024; i += 256) {
    int f = i >> 4, gq = (i & 15) << 2;
    *(ushort4*)&AFW[f * 66 + gq] = *(const ushort4*)&asrc[f * 64 + gq];
  }
  __syncthreads();

  const float wv = weight[0];
  const float gate = 1.0f / (1.0f + __expf(-fgate[0]));
  const float cg = wv * gate;           // freq coefficient
  const float cp = wv * (1.0f - gate);  // time-softmax coefficient
  const float c2 = 1.0f - wv;           // att_map coefficient
  unsigned short* psc = Psc[w];

  // ---- prologue: Wf[f][d] = sum_s AF256[f][s] * V[s][d]  (K=256 MFMA) ----
  {
    const int fA = w * 16 + lr;  // A: m = lane&15
    f32x4 wacc[4];
#pragma unroll
    for (int nt = 0; nt < 4; ++nt) wacc[nt] = (f32x4){0.f, 0.f, 0.f, 0.f};
#pragma unroll
    for (int kc = 0; kc < 8; ++kc) {
      bf16x8 afr;
#pragma unroll
      for (int i = 0; i < 8; ++i) {
        const int s = kc * 32 + lg * 8 + i;
        float srcg = fmaxf((s + 0.5f) * 0.25f - 0.5f, 0.0f);
        int g0 = (int)srcg;
        float wc = srcg - (float)g0;
        int g1 = g0 + 1;
        if (g1 > 63) g1 = 63;
        float v = bf2f(AFW[fA * 66 + g0]) * (1.0f - wc) + bf2f(AFW[fA * 66 + g1]) * wc;
        afr[i] = (short)f2bf(v);
      }
      const int s0 = kc * 32 + lg * 8;
#pragma unroll
      for (int nt = 0; nt < 4; ++nt) {
        const int d = nt * 16 + lr;
        const int off = d * 512 + ((s0 * 2) ^ ((d & 7) << 4));
        bf16x8 bv = *(bf16x8*)((char*)Vt + off);
        wacc[nt] = __builtin_amdgcn_mfma_f32_16x16x32_bf16(afr, bv, wacc[nt], 0, 0, 0);
      }
    }
    __syncthreads();  // all waves done reading afl
    // write Wf over afl: D row f = w*16+lg*4+j, col d = nt*16+lr
#pragma unroll
    for (int nt = 0; nt < 4; ++nt) {
#pragma unroll
      for (int j = 0; j < 4; ++j) {
        AFW[(w * 16 + lg * 4 + j) * 66 + nt * 16 + lr] = f2bf(wacc[nt][j]);
      }
    }
    __syncthreads();
  }

  // ---- tile-0 Q frag prefetch ----
  bf16x8 rq[2];
  {
    const unsigned short* qrow = qbase + (w * 64 + lr) * 64 + lg * 8;
    rq[0] = *(const bf16x8*)(qrow);
    rq[1] = *(const bf16x8*)(qrow + 32);
  }

  for (int tt = 0; tt < 4; ++tt) {
    const int tw = w * 64 + tt * 16;
    const float* amrow = amh + (size_t)(tw + lr) * 256 + lg * 8;

    bf16x8 aq[2] = {rq[0], rq[1]};

    // ---- QK^T ----
    f32x4 S[16];
#pragma unroll
    for (int nt = 0; nt < 16; ++nt) {
      f32x4 accv = {0.f, 0.f, 0.f, 0.f};
#pragma unroll
      for (int kc = 0; kc < 2; ++kc) {
        int srow = nt * 16 + lr;
        int d0 = kc * 32 + lg * 8;
        int off = srow * 128 + ((d0 * 2) ^ ((srow & 7) << 4));
        bf16x8 bk = *(bf16x8*)((char*)Ks + off);
        accv = __builtin_amdgcn_mfma_f32_16x16x32_bf16(aq[kc], bk, accv, 0, 0, 0);
      }
      S[nt] = accv;
    }

    // ---- prefetch next tile's Q ----
    if (tt < 3) {
      const unsigned short* qrow = qbase + (tw + 16 + lr) * 64 + lg * 8;
      rq[0] = *(const bf16x8*)(qrow);
      rq[1] = *(const bf16x8*)(qrow + 32);
    }

    // ---- softmax (16-lane xor groups) ----
    float c1j[4];
#pragma unroll
    for (int j = 0; j < 4; ++j) {
      float m = -1e30f;
#pragma unroll
      for (int nt = 0; nt < 16; ++nt) m = fmaxf(m, S[nt][j]);
#pragma unroll
      for (int mask = 1; mask < 16; mask <<= 1) m = fmaxf(m, __shfl_xor(m, mask));
      float rs = 0.f;
#pragma unroll
      for (int nt = 0; nt < 16; ++nt) {
        float e = __expf((S[nt][j] - m) * SCALE);
        S[nt][j] = e;
        rs += e;
      }
#pragma unroll
      for (int mask = 1; mask < 16; mask <<= 1) rs += __shfl_xor(rs, mask);
      c1j[j] = cp / rs;
    }

    // ---- PV with am folded into A-frag (am float4 loads, 1-deep pipeline) ----
    f32x4 O[4];
#pragma unroll
    for (int dt = 0; dt < 4; ++dt) O[dt] = (f32x4){0.f, 0.f, 0.f, 0.f};
    float4 am0 = *(const float4*)(amrow);
    float4 am1 = *(const float4*)(amrow + 4);
#pragma unroll
    for (int sb = 0; sb < 8; ++sb) {
      float4 nx0, nx1;
      if (sb < 7) {
        nx0 = *(const float4*)(amrow + (sb + 1) * 32);
        nx1 = *(const float4*)(amrow + (sb + 1) * 32 + 4);
      }
#pragma unroll
      for (int half = 0; half < 2; ++half) {
        const int nt = sb * 2 + half;
#pragma unroll
        for (int j = 0; j < 4; ++j) {
          psc[(lg * 4 + j) * 40 + half * 16 + lr] = f2bf(c1j[j] * S[nt][j]);
        }
      }
      bf16x8 praw = *(bf16x8*)&psc[lr * 40 + lg * 8];
      bf16x8 pa;
      {
        float av[8] = {am0.x, am0.y, am0.z, am0.w, am1.x, am1.y, am1.z, am1.w};
#pragma unroll
        for (int i = 0; i < 8; ++i) {
          pa[i] = (short)f2bf(bf2f((unsigned short)praw[i]) + c2 * av[i]);
        }
      }
      const int s0 = sb * 32 + lg * 8;
#pragma unroll
      for (int dt = 0; dt < 4; ++dt) {
        const int d = dt * 16 + lr;
        int off = d * 512 + ((s0 * 2) ^ ((d & 7) << 4));
        bf16x8 bv = *(bf16x8*)((char*)Vt + off);
        O[dt] = __builtin_amdgcn_mfma_f32_16x16x32_bf16(pa, bv, O[dt], 0, 0, 0);
      }
      am0 = nx0;
      am1 = nx1;
    }

    // ---- add freq term via Wf interp + write out_perm ----
#pragma unroll
    for (int j = 0; j < 4; ++j) {
      const int t = tw + lg * 4 + j;
      float srcf = fmaxf((t + 0.5f) * (129.0f / 256.0f) - 0.5f, 0.0f);
      int f0r = (int)srcf;
      float wf = srcf - (float)f0r;
      int f1r = f0r + 1;
      const bool v0 = (f0r < 64), v1 = (f1r < 64);
      float* orow = out_perm + ((size_t)((b * 256 + t) * 17 + jj)) * 512 + h * 64;
#pragma unroll
      for (int dt = 0; dt < 4; ++dt) {
        const int d = dt * 16 + lr;
        float fv = 0.f;
        if (v0) fv += (1.0f - wf) * bf2f(AFW[f0r * 66 + d]);
        if (v1) fv += wf * bf2f(AFW[f1r * 66 + d]);
        orow[d] = O[dt][j] + cg * fv;
      }
    }
  }
}

// ---------------- K4: d_out = out_perm @ w_proj + b_proj (split-bf16 MFMA) --------
__global__ __launch_bounds__(256, 2) void proj_gemm(
    const float* __restrict__ A,
    const unsigned short* __restrict__ wh, const unsigned short* __restrict__ wl,
    const float* __restrict__ bias, float* __restrict__ out) {
  __shared__ __attribute__((aligned(16))) unsigned short Wt[2][128 * LSTR];
  __shared__ __attribute__((aligned(16))) unsigned short Xt[2][128 * LSTR];

  const int tid = threadIdx.x;
  const int bx = blockIdx.x, by = blockIdx.y;
  const int wid = tid >> 6, lane = tid & 63;
  const int lr = lane & 15, lg = lane >> 4;
  const int wr = wid >> 1, wc = wid & 1;
  const int srow = tid >> 3, skg = tid & 7;

  const float* ap = A + (size_t)(by * 128 + srow) * 512 + skg * 8;
  const unsigned short* whp = wh + (size_t)(bx * 128 + srow) * 512 + skg * 8;
  const unsigned short* wlp = wl + (size_t)(bx * 128 + srow) * 512 + skg * 8;

  float4 rA[4][2];
  u16x8 rwh[4], rwl[4];
  auto loadk = [&](int k0) {
#pragma unroll
    for (int it = 0; it < 4; ++it) {
      const size_t o = (size_t)(32 * it) * 512 + k0;
      rA[it][0] = *(const float4*)(ap + o);
      rA[it][1] = *(const float4*)(ap + o + 4);
      rwh[it] = *(const u16x8*)(whp + o);
      rwl[it] = *(const u16x8*)(wlp + o);
    }
  };

  f32x4 acc[4][4];
#pragma unroll
  for (int nt = 0; nt < 4; ++nt)
#pragma unroll
    for (int mt = 0; mt < 4; ++mt) acc[nt][mt] = (f32x4){0.f, 0.f, 0.f, 0.f};

  loadk(0);
  for (int s = 0; s < 8; ++s) {
    if (s) __syncthreads();
#pragma unroll
    for (int it = 0; it < 4; ++it) {
      const int base = (srow + 32 * it) * LSTR + skg * 8;
      float vv[8] = {rA[it][0].x, rA[it][0].y, rA[it][0].z, rA[it][0].w,
                     rA[it][1].x, rA[it][1].y, rA[it][1].z, rA[it][1].w};
      u16x8 hi, lo;
#pragma unroll
      for (int e = 0; e < 8; ++e) {
        unsigned short h = f2bf(vv[e]);
        hi[e] = h;
        lo[e] = f2bf(vv[e] - bf2f(h));
      }
      *(u16x8*)&Xt[0][base] = hi;
      *(u16x8*)&Xt[1][base] = lo;
      *(u16x8*)&Wt[0][base] = rwh[it];
      *(u16x8*)&Wt[1][base] = rwl[it];
    }
    __syncthreads();
    if (s < 7) loadk((s + 1) * 64);
#pragma unroll
    for (int kh2 = 0; kh2 < 2; ++kh2) {
      const int kbase = kh2 * 32 + lg * 8;
      bf16x8 Ah[4], Al[4], Bh[4], Bl[4];
#pragma unroll
      for (int nt = 0; nt < 4; ++nt) {
        const int n = wr * 64 + nt * 16 + lr;
        Ah[nt] = *(bf16x8*)&Wt[0][n * LSTR + kbase];
        Al[nt] = *(bf16x8*)&Wt[1][n * LSTR + kbase];
      }
#pragma unroll
      for (int mt = 0; mt < 4; ++mt) {
        const int m = wc * 64 + mt * 16 + lr;
        Bh[mt] = *(bf16x8*)&Xt[0][m * LSTR + kbase];
        Bl[mt] = *(bf16x8*)&Xt[1][m * LSTR + kbase];
      }
#pragma unroll
      for (int nt = 0; nt < 4; ++nt)
#pragma unroll
        for (int mt = 0; mt < 4; ++mt) {
          acc[nt][mt] = __builtin_amdgcn_mfma_f32_16x16x32_bf16(Ah[nt], Bh[mt], acc[nt][mt], 0, 0, 0);
          acc[nt][mt] = __builtin_amdgcn_mfma_f32_16x16x32_bf16(Ah[nt], Bl[mt], acc[nt][mt], 0, 0, 0);
          acc[nt][mt] = __builtin_amdgcn_mfma_f32_16x16x32_bf16(Al[nt], Bh[mt], acc[nt][mt], 0, 0, 0);
        }
    }
  }

#pragma unroll
  for (int mt = 0; mt < 4; ++mt) {
    const int m = by * 128 + wc * 64 + mt * 16 + lr;
#pragma unroll
    for (int nt = 0; nt < 4; ++nt) {
      const int n = bx * 128 + wr * 64 + nt * 16 + lg * 4;
      float4 bi = *(const float4*)&bias[n];
      *(float4*)&out[(size_t)m * 512 + n] =
          make_float4(acc[nt][mt][0] + bi.x, acc[nt][mt][1] + bi.y,
                      acc[nt][mt][2] + bi.z, acc[nt][mt][3] + bi.w);
    }
  }
}

extern "C" void kernel_launch(void* const* d_in, const int* in_sizes, int n_in,
                              void* d_out, int out_size, void* d_ws, size_t ws_size,
                              hipStream_t stream) {
  (void)in_sizes; (void)n_in; (void)out_size; (void)ws_size;
  const float* x = (const float*)d_in[0];
  const float* att_map = (const float*)d_in[1];
  const float* weight = (const float*)d_in[2];
  const float* w_qkv = (const float*)d_in[3];
  const float* w_proj = (const float*)d_in[4];
  const float* b_proj = (const float*)d_in[5];
  const float* fgate = (const float*)d_in[6];
  float* out = (float*)d_out;

  char* ws = (char*)d_ws;
  const size_t PB = 17825792;  // one bf16 plane: 544*16384*2 B
  unsigned short* qh = (unsigned short*)(ws);
  unsigned short* ql = (unsigned short*)(ws + PB);
  unsigned short* kh = (unsigned short*)(ws + 2 * PB);
  unsigned short* kl = (unsigned short*)(ws + 3 * PB);
  unsigned short* vt = (unsigned short*)(ws + 4 * PB);
  unsigned short* af = (unsigned short*)(ws + 5 * PB);  // 544*4096 bf16
  char* base = ws + 5 * PB + 4456448;
  unsigned short* xh = (unsigned short*)(base);
  unsigned short* xl = (unsigned short*)(base + PB);
  float* out_perm = (float*)(base);  // alias xh/xl (disjoint lifetimes)
  unsigned short* wqh = (unsigned short*)(base + 35651584);
  unsigned short* wql = (unsigned short*)(base + 35651584 + 1572864);
  unsigned short* wph = (unsigned short*)(base + 35651584 + 2 * 1572864);
  unsigned short* wpl = (unsigned short*)(base + 35651584 + 2 * 1572864 + 524288);

  conv_x<<<4352, 256, 0, stream>>>(x, xh, xl);
  conv_wT<<<dim3(24, 8), 256, 0, stream>>>(w_qkv, wqh, wql, 1536);
  conv_wT<<<dim3(8, 8), 256, 0, stream>>>(w_proj, wph, wpl, 512);
  qkv_gemm<<<dim3(12, 136), 256, 0, stream>>>(xh, xl, wqh, wql, qh, ql, kh, kl, vt);
  freq_kernel<<<544, 256, 0, stream>>>(qh, ql, kh, kl, af);
  attn_kernel<<<544, 256, 0, stream>>>(qh, kh, vt, af, att_map, weight, fgate,
                                       out_perm);
  proj_gemm<<<dim3(4, 136), 256, 0, stream>>>(out_perm, wph, wpl, b_proj, out);
}

// Round 16
// 351.432 us; speedup vs baseline: 2.4199x; 1.0788x over previous
//
#include <hip/hip_runtime.h>
#include <hip/hip_bf16.h>

// FrequencyAwareSumAttention — round 16: K1 index remap only.
// (1) jj-grouped m-tiles: block rows share (b,jj), t consecutive -> coalesced
//     vt/qh/kh epilogue writes (kills the ~70MB write amplification).
// (2) bijective XCD-chunked block swizzle (1632 = 8*204): the 12 n-tile blocks
//     sharing an x-tile run on one XCD's L2.
// K0/K2/K3/K4 byte-identical to round 15 (379us build).

#define SCALE 0.125f
#define LSTR 72

typedef __attribute__((ext_vector_type(4))) float f32x4;
typedef __attribute__((ext_vector_type(8))) short bf16x8;
typedef __attribute__((ext_vector_type(8))) unsigned short u16x8;

__device__ __forceinline__ float bf2f(unsigned short u) {
  return __uint_as_float(((unsigned int)u) << 16);
}
__device__ __forceinline__ unsigned short f2bf(float f) {
  unsigned int u = __float_as_uint(f);
  u += 0x7FFFu + ((u >> 16) & 1u);
  return (unsigned short)(u >> 16);
}

// ---------------- K0a: x fp32 -> hi/lo bf16 planes ----------------
__global__ __launch_bounds__(256) void conv_x(
    const float* __restrict__ x, unsigned short* __restrict__ xh,
    unsigned short* __restrict__ xl) {
  const size_t i = ((size_t)blockIdx.x * 256 + threadIdx.x) * 8;
  float4 a = *(const float4*)(x + i);
  float4 b = *(const float4*)(x + i + 4);
  float vv[8] = {a.x, a.y, a.z, a.w, b.x, b.y, b.z, b.w};
  u16x8 hi, lo;
#pragma unroll
  for (int e = 0; e < 8; ++e) {
    unsigned short h = f2bf(vv[e]);
    hi[e] = h;
    lo[e] = f2bf(vv[e] - bf2f(h));
  }
  *(u16x8*)&xh[i] = hi;
  *(u16x8*)&xl[i] = lo;
}

// ---------------- K0b: w [K=512][N] -> transposed [N][512] hi/lo planes ----------
__global__ __launch_bounds__(256) void conv_wT(
    const float* __restrict__ w, unsigned short* __restrict__ th,
    unsigned short* __restrict__ tl, int N) {
  __shared__ float T[64][65];
  const int tid = threadIdx.x;
  const int nt = blockIdx.x * 64, kt = blockIdx.y * 64;
  for (int i = tid; i < 4096; i += 256) {
    const int r = i >> 6, c = i & 63;
    T[r][c] = w[(size_t)(kt + r) * N + nt + c];
  }
  __syncthreads();
  for (int i = tid; i < 4096; i += 256) {
    const int rn = i >> 6, ck = i & 63;
    const float v = T[ck][rn];
    const unsigned short h = f2bf(v);
    const size_t o = (size_t)(nt + rn) * 512 + kt + ck;
    th[o] = h;
    tl[o] = f2bf(v - bf2f(h));
  }
}

// ---------------- K1: qkv = x @ w_qkv (split-bf16 MFMA) -> bf16 planes ----------
// Grid: 1632 blocks (12 n-tiles x 136 m-tiles), XCD-chunk swizzled.
// m-tile = (b, jj, t0): rows share (b,jj); t = t0 + 0..127 (consecutive).
__global__ __launch_bounds__(256, 2) void qkv_gemm(
    const unsigned short* __restrict__ xh, const unsigned short* __restrict__ xl,
    const unsigned short* __restrict__ wh, const unsigned short* __restrict__ wl,
    unsigned short* __restrict__ qh, unsigned short* __restrict__ ql,
    unsigned short* __restrict__ kh, unsigned short* __restrict__ kl,
    unsigned short* __restrict__ vt) {
  __shared__ __attribute__((aligned(16))) unsigned short Wt[2][128 * LSTR];
  __shared__ __attribute__((aligned(16))) unsigned short Xt[2][128 * LSTR];

  const int tid = threadIdx.x;
  // bijective XCD-chunk swizzle: 1632 = 8 * 204
  const int lin = blockIdx.x;
  const int swz = (lin & 7) * 204 + (lin >> 3);
  const int by = swz / 12, bx = swz % 12;
  const int pair = by >> 1;            // (b, jj)
  const int t0 = (by & 1) << 7;        // 0 or 128
  const int b = pair / 17;
  const int jj = pair % 17;

  const int wid = tid >> 6, lane = tid & 63;
  const int lr = lane & 15, lg = lane >> 4;
  const int wr = wid >> 1, wc = wid & 1;
  const int srow = tid >> 3, skg = tid & 7;

  // x row for srow: rowidx = ((b*256 + t0 + srow)*17 + jj); stride/row = 17*512
  const size_t xrow0 = ((size_t)((b * 256 + t0 + srow) * 17 + jj)) * 512 + skg * 8;
  const unsigned short* xhp = xh + xrow0;
  const unsigned short* xlp = xl + xrow0;
  const unsigned short* whp = wh + (size_t)(bx * 128 + srow) * 512 + skg * 8;
  const unsigned short* wlp = wl + (size_t)(bx * 128 + srow) * 512 + skg * 8;

  u16x8 rxh[4], rxl[4], rwh[4], rwl[4];
  auto loadk = [&](int k0) {
#pragma unroll
    for (int it = 0; it < 4; ++it) {
      const size_t ox = (size_t)(32 * it) * 8704 + k0;  // 32 rows * 17*512
      const size_t ow = (size_t)(32 * it) * 512 + k0;
      rxh[it] = *(const u16x8*)(xhp + ox);
      rxl[it] = *(const u16x8*)(xlp + ox);
      rwh[it] = *(const u16x8*)(whp + ow);
      rwl[it] = *(const u16x8*)(wlp + ow);
    }
  };

  f32x4 acc[4][4];
#pragma unroll
  for (int nt = 0; nt < 4; ++nt)
#pragma unroll
    for (int mt = 0; mt < 4; ++mt) acc[nt][mt] = (f32x4){0.f, 0.f, 0.f, 0.f};

  loadk(0);
  for (int s = 0; s < 8; ++s) {
    if (s) __syncthreads();
#pragma unroll
    for (int it = 0; it < 4; ++it) {
      const int base = (srow + 32 * it) * LSTR + skg * 8;
      *(u16x8*)&Xt[0][base] = rxh[it];
      *(u16x8*)&Xt[1][base] = rxl[it];
      *(u16x8*)&Wt[0][base] = rwh[it];
      *(u16x8*)&Wt[1][base] = rwl[it];
    }
    __syncthreads();
    if (s < 7) loadk((s + 1) * 64);
#pragma unroll
    for (int kh2 = 0; kh2 < 2; ++kh2) {
      const int kbase = kh2 * 32 + lg * 8;
      bf16x8 Ah[4], Al[4], Bh[4], Bl[4];
#pragma unroll
      for (int nt = 0; nt < 4; ++nt) {
        const int n = wr * 64 + nt * 16 + lr;
        Ah[nt] = *(bf16x8*)&Wt[0][n * LSTR + kbase];
        Al[nt] = *(bf16x8*)&Wt[1][n * LSTR + kbase];
      }
#pragma unroll
      for (int mt = 0; mt < 4; ++mt) {
        const int m = wc * 64 + mt * 16 + lr;
        Bh[mt] = *(bf16x8*)&Xt[0][m * LSTR + kbase];
        Bl[mt] = *(bf16x8*)&Xt[1][m * LSTR + kbase];
      }
#pragma unroll
      for (int nt = 0; nt < 4; ++nt)
#pragma unroll
        for (int mt = 0; mt < 4; ++mt) {
          acc[nt][mt] = __builtin_amdgcn_mfma_f32_16x16x32_bf16(Ah[nt], Bh[mt], acc[nt][mt], 0, 0, 0);
          acc[nt][mt] = __builtin_amdgcn_mfma_f32_16x16x32_bf16(Ah[nt], Bl[mt], acc[nt][mt], 0, 0, 0);
          acc[nt][mt] = __builtin_amdgcn_mfma_f32_16x16x32_bf16(Al[nt], Bh[mt], acc[nt][mt], 0, 0, 0);
        }
    }
  }

  // epilogue: t = t0 + wc*64 + mt*16 + lr (consecutive across lr); (b,jj) fixed.
#pragma unroll
  for (int mt = 0; mt < 4; ++mt) {
    const int t = t0 + wc * 64 + mt * 16 + lr;
#pragma unroll
    for (int nt = 0; nt < 4; ++nt) {
      const int c = bx * 128 + wr * 64 + nt * 16 + lg * 4;
      const int qi = c >> 9;
      const int h = (c >> 6) & 7;
      const int dd = c & 63;
      const size_t hdbase = ((size_t)((b * 8 + h) * 17 + jj)) * 16384;
      float a0 = acc[nt][mt][0], a1 = acc[nt][mt][1], a2 = acc[nt][mt][2],
            a3 = acc[nt][mt][3];
      ushort4 hi4 = make_ushort4(f2bf(a0), f2bf(a1), f2bf(a2), f2bf(a3));
      if (qi == 2) {
        vt[hdbase + (size_t)(dd + 0) * 256 + t] = hi4.x;
        vt[hdbase + (size_t)(dd + 1) * 256 + t] = hi4.y;
        vt[hdbase + (size_t)(dd + 2) * 256 + t] = hi4.z;
        vt[hdbase + (size_t)(dd + 3) * 256 + t] = hi4.w;
      } else {
        ushort4 lo4 = make_ushort4(f2bf(a0 - bf2f(hi4.x)), f2bf(a1 - bf2f(hi4.y)),
                                   f2bf(a2 - bf2f(hi4.z)), f2bf(a3 - bf2f(hi4.w)));
        unsigned short* dh = qi ? kh : qh;
        unsigned short* dl = qi ? kl : ql;
        *(ushort4*)&dh[hdbase + t * 64 + dd] = hi4;
        *(ushort4*)&dl[hdbase + t * 64 + dd] = lo4;
      }
    }
  }
}

// ---------------- K2: MFMA DFT from bf16 planes + af GEMM + softmax -> af bf16 ----
__global__ __launch_bounds__(256) void freq_kernel(
    const unsigned short* __restrict__ qhp, const unsigned short* __restrict__ qlp,
    const unsigned short* __restrict__ khp, const unsigned short* __restrict__ klp,
    unsigned short* __restrict__ af_out) {
  __shared__ __attribute__((aligned(16))) unsigned short qT[2][64 * 256];
  __shared__ __attribute__((aligned(16))) unsigned short QF[4][64 * 64];
  __shared__ __attribute__((aligned(16))) unsigned short KF[4][64 * 64];

  const int tid = threadIdx.x;
  const int head = blockIdx.x;
  const int w = tid >> 6, lane = tid & 63;
  const int lr = lane & 15, lg = lane >> 4;
  const int f0 = w << 4;

  bf16x8 Ech[8], Ecl[8], Esh[8], Esl[8];
  {
    const int f = f0 + lr;
#pragma unroll
    for (int kb = 0; kb < 8; ++kb) {
      bf16x8 ch, cl, sh, sl;
#pragma unroll
      for (int i = 0; i < 8; ++i) {
        int t = kb * 32 + lg * 8 + i;
        int idx = (f * t) & 255;
        float s, c;
        __sincosf((float)idx * 0.02454369260617026f, &s, &c);
        unsigned short chh = f2bf(c);
        unsigned short shh = f2bf(s);
        ch[i] = (short)chh;
        cl[i] = (short)f2bf(c - bf2f(chh));
        sh[i] = (short)shh;
        sl[i] = (short)f2bf(s - bf2f(shh));
      }
      Ech[kb] = ch; Ecl[kb] = cl; Esh[kb] = sh; Esl[kb] = sl;
    }
  }

  for (int pass = 0; pass < 2; ++pass) {
    const unsigned short* sh_ = (pass ? khp : qhp) + head * 16384;
    const unsigned short* sl_ = (pass ? klp : qlp) + head * 16384;
    __syncthreads();
    for (int i = tid; i < 4096; i += 256) {
      int t = i >> 4, dq = i & 15;
      ushort4 hv = *(const ushort4*)&sh_[t * 64 + dq * 4];
      ushort4 lv = *(const ushort4*)&sl_[t * 64 + dq * 4];
      unsigned short hvv[4] = {hv.x, hv.y, hv.z, hv.w};
      unsigned short lvv[4] = {lv.x, lv.y, lv.z, lv.w};
#pragma unroll
      for (int c = 0; c < 4; ++c) {
        int d = dq * 4 + c;
        int byo = d * 512 + ((t * 2) ^ ((d & 31) << 4));
        *(unsigned short*)((char*)qT[0] + byo) = hvv[c];
        *(unsigned short*)((char*)qT[1] + byo) = lvv[c];
      }
    }
    __syncthreads();

    f32x4 ar[4], ai[4];
#pragma unroll
    for (int nt = 0; nt < 4; ++nt) {
      ar[nt] = (f32x4){0.f, 0.f, 0.f, 0.f};
      ai[nt] = (f32x4){0.f, 0.f, 0.f, 0.f};
    }
#pragma unroll
    for (int kb = 0; kb < 8; ++kb) {
#pragma unroll
      for (int nt = 0; nt < 4; ++nt) {
        const int d = nt * 16 + lr;
        const int byo = d * 512 + ((kb * 64 + lg * 16) ^ ((d & 31) << 4));
        bf16x8 bh = *(bf16x8*)((char*)qT[0] + byo);
        bf16x8 bl = *(bf16x8*)((char*)qT[1] + byo);
        ar[nt] = __builtin_amdgcn_mfma_f32_16x16x32_bf16(Ech[kb], bh, ar[nt], 0, 0, 0);
        ar[nt] = __builtin_amdgcn_mfma_f32_16x16x32_bf16(Ech[kb], bl, ar[nt], 0, 0, 0);
        ar[nt] = __builtin_amdgcn_mfma_f32_16x16x32_bf16(Ecl[kb], bh, ar[nt], 0, 0, 0);
        ai[nt] = __builtin_amdgcn_mfma_f32_16x16x32_bf16(Esh[kb], bh, ai[nt], 0, 0, 0);
        ai[nt] = __builtin_amdgcn_mfma_f32_16x16x32_bf16(Esh[kb], bl, ai[nt], 0, 0, 0);
        ai[nt] = __builtin_amdgcn_mfma_f32_16x16x32_bf16(Esl[kb], bh, ai[nt], 0, 0, 0);
      }
    }
    unsigned short(*DST)[64 * 64] = pass ? KF : QF;
#pragma unroll
    for (int nt = 0; nt < 4; ++nt) {
#pragma unroll
      for (int j = 0; j < 4; ++j) {
        const int f = f0 + lg * 4 + j;
        const int d = nt * 16 + lr;
        const int byo = f * 128 + ((d * 2) ^ ((f & 7) << 4));
        float vr = ar[nt][j], vi = ai[nt][j];
        unsigned short rh = f2bf(vr);
        unsigned short ih = f2bf(vi);
        *(unsigned short*)((char*)DST[0] + byo) = rh;
        *(unsigned short*)((char*)DST[1] + byo) = f2bf(vr - bf2f(rh));
        *(unsigned short*)((char*)DST[2] + byo) = ih;
        *(unsigned short*)((char*)DST[3] + byo) = f2bf(vi - bf2f(ih));
      }
    }
  }
  __syncthreads();

  f32x4 acc[4];
#pragma unroll
  for (int nt = 0; nt < 4; ++nt) acc[nt] = (f32x4){0.f, 0.f, 0.f, 0.f};
#pragma unroll
  for (int kb = 0; kb < 2; ++kb) {
    const int fA = f0 + lr;
    const int abyo = fA * 128 + ((kb * 64 + lg * 16) ^ ((fA & 7) << 4));
    bf16x8 arh = *(bf16x8*)((char*)QF[0] + abyo);
    bf16x8 arl = *(bf16x8*)((char*)QF[1] + abyo);
    bf16x8 aih = *(bf16x8*)((char*)QF[2] + abyo);
    bf16x8 ail = *(bf16x8*)((char*)QF[3] + abyo);
#pragma unroll
    for (int nt = 0; nt < 4; ++nt) {
      const int g = nt * 16 + lr;
      const int bbyo = g * 128 + ((kb * 64 + lg * 16) ^ ((g & 7) << 4));
      bf16x8 brh = *(bf16x8*)((char*)KF[0] + bbyo);
      bf16x8 brl = *(bf16x8*)((char*)KF[1] + bbyo);
      bf16x8 bih = *(bf16x8*)((char*)KF[2] + bbyo);
      bf16x8 bil = *(bf16x8*)((char*)KF[3] + bbyo);
      acc[nt] = __builtin_amdgcn_mfma_f32_16x16x32_bf16(arh, brh, acc[nt], 0, 0, 0);
      acc[nt] = __builtin_amdgcn_mfma_f32_16x16x32_bf16(arh, brl, acc[nt], 0, 0, 0);
      acc[nt] = __builtin_amdgcn_mfma_f32_16x16x32_bf16(arl, brh, acc[nt], 0, 0, 0);
      acc[nt] = __builtin_amdgcn_mfma_f32_16x16x32_bf16(aih, bih, acc[nt], 0, 0, 0);
      acc[nt] = __builtin_amdgcn_mfma_f32_16x16x32_bf16(aih, bil, acc[nt], 0, 0, 0);
      acc[nt] = __builtin_amdgcn_mfma_f32_16x16x32_bf16(ail, bih, acc[nt], 0, 0, 0);
    }
  }

  unsigned short* outh = af_out + head * 4096;
#pragma unroll
  for (int j = 0; j < 4; ++j) {
    float m = fmaxf(fmaxf(acc[0][j], acc[1][j]), fmaxf(acc[2][j], acc[3][j]));
#pragma unroll
    for (int mask = 1; mask < 16; mask <<= 1) m = fmaxf(m, __shfl_xor(m, mask));
    float e[4];
    float rs = 0.f;
#pragma unroll
    for (int nt = 0; nt < 4; ++nt) {
      e[nt] = __expf((acc[nt][j] - m) * SCALE);
      rs += e[nt];
    }
#pragma unroll
    for (int mask = 1; mask < 16; mask <<= 1) rs += __shfl_xor(rs, mask);
    const float inv = 1.0f / rs;
    const int f = f0 + lg * 4 + j;
#pragma unroll
    for (int nt = 0; nt < 4; ++nt) outh[f * 64 + nt * 16 + lr] = f2bf(e[nt] * inv);
  }
}

// ---------------- K3: attn with Wf prologue + am-in-A-frag (round-15, 134us) -----
__global__ __launch_bounds__(256) void attn_kernel(
    const unsigned short* __restrict__ qhp, const unsigned short* __restrict__ khp,
    const unsigned short* __restrict__ vtp, const unsigned short* __restrict__ af,
    const float* __restrict__ att_map, const float* __restrict__ weight,
    const float* __restrict__ fgate, float* __restrict__ out_perm) {
  __shared__ unsigned short Ks[256 * 64];
  __shared__ unsigned short Vt[64 * 256];
  __shared__ unsigned short AFW[64 * 66];
  __shared__ unsigned short Psc[4][16 * 40];

  const int tid = threadIdx.x;
  const int head = blockIdx.x;
  const int jj = head % 17;
  const int hb = head / 17;
  const int h = hb & 7;
  const int b = hb >> 3;
  const int w = tid >> 6, lane = tid & 63;
  const int lr = lane & 15, lg = lane >> 4;

  const float* amh = att_map + (size_t)head * 65536;
  const unsigned short* qbase = qhp + head * 16384;

  const unsigned short* ksrc = khp + head * 16384;
  const unsigned short* vsrc = vtp + head * 16384;
  for (int i = tid; i < 2048; i += 256) {
    int s = i >> 3, dq8 = i & 7;
    u16x8 kv = *(const u16x8*)&ksrc[s * 64 + dq8 * 8];
    int koff = s * 128 + ((dq8 * 16) ^ ((s & 7) << 4));
    *(u16x8*)((char*)Ks + koff) = kv;
    int d = i >> 5, t8 = i & 31;
    u16x8 vv = *(const u16x8*)&vsrc[d * 256 + t8 * 8];
    int voff = d * 512 + ((t8 * 16) ^ ((d & 7) << 4));
    *(u16x8*)((char*)Vt + voff) = vv;
  }
  const unsigned short* asrc = af + head * 4096;
  for (int i = tid; i < 1024; i += 256) {
    int f = i >> 4, gq = (i & 15) << 2;
    *(ushort4*)&AFW[f * 66 + gq] = *(const ushort4*)&asrc[f * 64 + gq];
  }
  __syncthreads();

  const float wv = weight[0];
  const float gate = 1.0f / (1.0f + __expf(-fgate[0]));
  const float cg = wv * gate;
  const float cp = wv * (1.0f - gate);
  const float c2 = 1.0f - wv;
  unsigned short* psc = Psc[w];

  // ---- prologue: Wf[f][d] = sum_s AF256[f][s] * V[s][d] ----
  {
    const int fA = w * 16 + lr;
    f32x4 wacc[4];
#pragma unroll
    for (int nt = 0; nt < 4; ++nt) wacc[nt] = (f32x4){0.f, 0.f, 0.f, 0.f};
#pragma unroll
    for (int kc = 0; kc < 8; ++kc) {
      bf16x8 afr;
#pragma unroll
      for (int i = 0; i < 8; ++i) {
        const int s = kc * 32 + lg * 8 + i;
        float srcg = fmaxf((s + 0.5f) * 0.25f - 0.5f, 0.0f);
        int g0 = (int)srcg;
        float wc = srcg - (float)g0;
        int g1 = g0 + 1;
        if (g1 > 63) g1 = 63;
        float v = bf2f(AFW[fA * 66 + g0]) * (1.0f - wc) + bf2f(AFW[fA * 66 + g1]) * wc;
        afr[i] = (short)f2bf(v);
      }
      const int s0 = kc * 32 + lg * 8;
#pragma unroll
      for (int nt = 0; nt < 4; ++nt) {
        const int d = nt * 16 + lr;
        const int off = d * 512 + ((s0 * 2) ^ ((d & 7) << 4));
        bf16x8 bv = *(bf16x8*)((char*)Vt + off);
        wacc[nt] = __builtin_amdgcn_mfma_f32_16x16x32_bf16(afr, bv, wacc[nt], 0, 0, 0);
      }
    }
    __syncthreads();
#pragma unroll
    for (int nt = 0; nt < 4; ++nt) {
#pragma unroll
      for (int j = 0; j < 4; ++j) {
        AFW[(w * 16 + lg * 4 + j) * 66 + nt * 16 + lr] = f2bf(wacc[nt][j]);
      }
    }
    __syncthreads();
  }

  bf16x8 rq[2];
  {
    const unsigned short* qrow = qbase + (w * 64 + lr) * 64 + lg * 8;
    rq[0] = *(const bf16x8*)(qrow);
    rq[1] = *(const bf16x8*)(qrow + 32);
  }

  for (int tt = 0; tt < 4; ++tt) {
    const int tw = w * 64 + tt * 16;
    const float* amrow = amh + (size_t)(tw + lr) * 256 + lg * 8;

    bf16x8 aq[2] = {rq[0], rq[1]};

    f32x4 S[16];
#pragma unroll
    for (int nt = 0; nt < 16; ++nt) {
      f32x4 accv = {0.f, 0.f, 0.f, 0.f};
#pragma unroll
      for (int kc = 0; kc < 2; ++kc) {
        int srow = nt * 16 + lr;
        int d0 = kc * 32 + lg * 8;
        int off = srow * 128 + ((d0 * 2) ^ ((srow & 7) << 4));
        bf16x8 bk = *(bf16x8*)((char*)Ks + off);
        accv = __builtin_amdgcn_mfma_f32_16x16x32_bf16(aq[kc], bk, accv, 0, 0, 0);
      }
      S[nt] = accv;
    }

    if (tt < 3) {
      const unsigned short* qrow = qbase + (tw + 16 + lr) * 64 + lg * 8;
      rq[0] = *(const bf16x8*)(qrow);
      rq[1] = *(const bf16x8*)(qrow + 32);
    }

    float c1j[4];
#pragma unroll
    for (int j = 0; j < 4; ++j) {
      float m = -1e30f;
#pragma unroll
      for (int nt = 0; nt < 16; ++nt) m = fmaxf(m, S[nt][j]);
#pragma unroll
      for (int mask = 1; mask < 16; mask <<= 1) m = fmaxf(m, __shfl_xor(m, mask));
      float rs = 0.f;
#pragma unroll
      for (int nt = 0; nt < 16; ++nt) {
        float e = __expf((S[nt][j] - m) * SCALE);
        S[nt][j] = e;
        rs += e;
      }
#pragma unroll
      for (int mask = 1; mask < 16; mask <<= 1) rs += __shfl_xor(rs, mask);
      c1j[j] = cp / rs;
    }

    f32x4 O[4];
#pragma unroll
    for (int dt = 0; dt < 4; ++dt) O[dt] = (f32x4){0.f, 0.f, 0.f, 0.f};
    float4 am0 = *(const float4*)(amrow);
    float4 am1 = *(const float4*)(amrow + 4);
#pragma unroll
    for (int sb = 0; sb < 8; ++sb) {
      float4 nx0, nx1;
      if (sb < 7) {
        nx0 = *(const float4*)(amrow + (sb + 1) * 32);
        nx1 = *(const float4*)(amrow + (sb + 1) * 32 + 4);
      }
#pragma unroll
      for (int half = 0; half < 2; ++half) {
        const int nt = sb * 2 + half;
#pragma unroll
        for (int j = 0; j < 4; ++j) {
          psc[(lg * 4 + j) * 40 + half * 16 + lr] = f2bf(c1j[j] * S[nt][j]);
        }
      }
      bf16x8 praw = *(bf16x8*)&psc[lr * 40 + lg * 8];
      bf16x8 pa;
      {
        float av[8] = {am0.x, am0.y, am0.z, am0.w, am1.x, am1.y, am1.z, am1.w};
#pragma unroll
        for (int i = 0; i < 8; ++i) {
          pa[i] = (short)f2bf(bf2f((unsigned short)praw[i]) + c2 * av[i]);
        }
      }
      const int s0 = sb * 32 + lg * 8;
#pragma unroll
      for (int dt = 0; dt < 4; ++dt) {
        const int d = dt * 16 + lr;
        int off = d * 512 + ((s0 * 2) ^ ((d & 7) << 4));
        bf16x8 bv = *(bf16x8*)((char*)Vt + off);
        O[dt] = __builtin_amdgcn_mfma_f32_16x16x32_bf16(pa, bv, O[dt], 0, 0, 0);
      }
      am0 = nx0;
      am1 = nx1;
    }

#pragma unroll
    for (int j = 0; j < 4; ++j) {
      const int t = tw + lg * 4 + j;
      float srcf = fmaxf((t + 0.5f) * (129.0f / 256.0f) - 0.5f, 0.0f);
      int f0r = (int)srcf;
      float wf = srcf - (float)f0r;
      int f1r = f0r + 1;
      const bool v0 = (f0r < 64), v1 = (f1r < 64);
      float* orow = out_perm + ((size_t)((b * 256 + t) * 17 + jj)) * 512 + h * 64;
#pragma unroll
      for (int dt = 0; dt < 4; ++dt) {
        const int d = dt * 16 + lr;
        float fv = 0.f;
        if (v0) fv += (1.0f - wf) * bf2f(AFW[f0r * 66 + d]);
        if (v1) fv += wf * bf2f(AFW[f1r * 66 + d]);
        orow[d] = O[dt][j] + cg * fv;
      }
    }
  }
}

// ---------------- K4: d_out = out_perm @ w_proj + b_proj (split-bf16 MFMA) --------
__global__ __launch_bounds__(256, 2) void proj_gemm(
    const float* __restrict__ A,
    const unsigned short* __restrict__ wh, const unsigned short* __restrict__ wl,
    const float* __restrict__ bias, float* __restrict__ out) {
  __shared__ __attribute__((aligned(16))) unsigned short Wt[2][128 * LSTR];
  __shared__ __attribute__((aligned(16))) unsigned short Xt[2][128 * LSTR];

  const int tid = threadIdx.x;
  const int bx = blockIdx.x, by = blockIdx.y;
  const int wid = tid >> 6, lane = tid & 63;
  const int lr = lane & 15, lg = lane >> 4;
  const int wr = wid >> 1, wc = wid & 1;
  const int srow = tid >> 3, skg = tid & 7;

  const float* ap = A + (size_t)(by * 128 + srow) * 512 + skg * 8;
  const unsigned short* whp = wh + (size_t)(bx * 128 + srow) * 512 + skg * 8;
  const unsigned short* wlp = wl + (size_t)(bx * 128 + srow) * 512 + skg * 8;

  float4 rA[4][2];
  u16x8 rwh[4], rwl[4];
  auto loadk = [&](int k0) {
#pragma unroll
    for (int it = 0; it < 4; ++it) {
      const size_t o = (size_t)(32 * it) * 512 + k0;
      rA[it][0] = *(const float4*)(ap + o);
      rA[it][1] = *(const float4*)(ap + o + 4);
      rwh[it] = *(const u16x8*)(whp + o);
      rwl[it] = *(const u16x8*)(wlp + o);
    }
  };

  f32x4 acc[4][4];
#pragma unroll
  for (int nt = 0; nt < 4; ++nt)
#pragma unroll
    for (int mt = 0; mt < 4; ++mt) acc[nt][mt] = (f32x4){0.f, 0.f, 0.f, 0.f};

  loadk(0);
  for (int s = 0; s < 8; ++s) {
    if (s) __syncthreads();
#pragma unroll
    for (int it = 0; it < 4; ++it) {
      const int base = (srow + 32 * it) * LSTR + skg * 8;
      float vv[8] = {rA[it][0].x, rA[it][0].y, rA[it][0].z, rA[it][0].w,
                     rA[it][1].x, rA[it][1].y, rA[it][1].z, rA[it][1].w};
      u16x8 hi, lo;
#pragma unroll
      for (int e = 0; e < 8; ++e) {
        unsigned short h = f2bf(vv[e]);
        hi[e] = h;
        lo[e] = f2bf(vv[e] - bf2f(h));
      }
      *(u16x8*)&Xt[0][base] = hi;
      *(u16x8*)&Xt[1][base] = lo;
      *(u16x8*)&Wt[0][base] = rwh[it];
      *(u16x8*)&Wt[1][base] = rwl[it];
    }
    __syncthreads();
    if (s < 7) loadk((s + 1) * 64);
#pragma unroll
    for (int kh2 = 0; kh2 < 2; ++kh2) {
      const int kbase = kh2 * 32 + lg * 8;
      bf16x8 Ah[4], Al[4], Bh[4], Bl[4];
#pragma unroll
      for (int nt = 0; nt < 4; ++nt) {
        const int n = wr * 64 + nt * 16 + lr;
        Ah[nt] = *(bf16x8*)&Wt[0][n * LSTR + kbase];
        Al[nt] = *(bf16x8*)&Wt[1][n * LSTR + kbase];
      }
#pragma unroll
      for (int mt = 0; mt < 4; ++mt) {
        const int m = wc * 64 + mt * 16 + lr;
        Bh[mt] = *(bf16x8*)&Xt[0][m * LSTR + kbase];
        Bl[mt] = *(bf16x8*)&Xt[1][m * LSTR + kbase];
      }
#pragma unroll
      for (int nt = 0; nt < 4; ++nt)
#pragma unroll
        for (int mt = 0; mt < 4; ++mt) {
          acc[nt][mt] = __builtin_amdgcn_mfma_f32_16x16x32_bf16(Ah[nt], Bh[mt], acc[nt][mt], 0, 0, 0);
          acc[nt][mt] = __builtin_amdgcn_mfma_f32_16x16x32_bf16(Ah[nt], Bl[mt], acc[nt][mt], 0, 0, 0);
          acc[nt][mt] = __builtin_amdgcn_mfma_f32_16x16x32_bf16(Al[nt], Bh[mt], acc[nt][mt], 0, 0, 0);
        }
    }
  }

#pragma unroll
  for (int mt = 0; mt < 4; ++mt) {
    const int m = by * 128 + wc * 64 + mt * 16 + lr;
#pragma unroll
    for (int nt = 0; nt < 4; ++nt) {
      const int n = bx * 128 + wr * 64 + nt * 16 + lg * 4;
      float4 bi = *(const float4*)&bias[n];
      *(float4*)&out[(size_t)m * 512 + n] =
          make_float4(acc[nt][mt][0] + bi.x, acc[nt][mt][1] + bi.y,
                      acc[nt][mt][2] + bi.z, acc[nt][mt][3] + bi.w);
    }
  }
}

extern "C" void kernel_launch(void* const* d_in, const int* in_sizes, int n_in,
                              void* d_out, int out_size, void* d_ws, size_t ws_size,
                              hipStream_t stream) {
  (void)in_sizes; (void)n_in; (void)out_size; (void)ws_size;
  const float* x = (const float*)d_in[0];
  const float* att_map = (const float*)d_in[1];
  const float* weight = (const float*)d_in[2];
  const float* w_qkv = (const float*)d_in[3];
  const float* w_proj = (const float*)d_in[4];
  const float* b_proj = (const float*)d_in[5];
  const float* fgate = (const float*)d_in[6];
  float* out = (float*)d_out;

  char* ws = (char*)d_ws;
  const size_t PB = 17825792;  // one bf16 plane: 544*16384*2 B
  unsigned short* qh = (unsigned short*)(ws);
  unsigned short* ql = (unsigned short*)(ws + PB);
  unsigned short* kh = (unsigned short*)(ws + 2 * PB);
  unsigned short* kl = (unsigned short*)(ws + 3 * PB);
  unsigned short* vt = (unsigned short*)(ws + 4 * PB);
  unsigned short* af = (unsigned short*)(ws + 5 * PB);  // 544*4096 bf16
  char* base = ws + 5 * PB + 4456448;
  unsigned short* xh = (unsigned short*)(base);
  unsigned short* xl = (unsigned short*)(base + PB);
  float* out_perm = (float*)(base);  // alias xh/xl (disjoint lifetimes)
  unsigned short* wqh = (unsigned short*)(base + 35651584);
  unsigned short* wql = (unsigned short*)(base + 35651584 + 1572864);
  unsigned short* wph = (unsigned short*)(base + 35651584 + 2 * 1572864);
  unsigned short* wpl = (unsigned short*)(base + 35651584 + 2 * 1572864 + 524288);

  conv_x<<<4352, 256, 0, stream>>>(x, xh, xl);
  conv_wT<<<dim3(24, 8), 256, 0, stream>>>(w_qkv, wqh, wql, 1536);
  conv_wT<<<dim3(8, 8), 256, 0, stream>>>(w_proj, wph, wpl, 512);
  qkv_gemm<<<1632, 256, 0, stream>>>(xh, xl, wqh, wql, qh, ql, kh, kl, vt);
  freq_kernel<<<544, 256, 0, stream>>>(qh, ql, kh, kl, af);
  attn_kernel<<<544, 256, 0, stream>>>(qh, kh, vt, af, att_map, weight, fgate,
                                       out_perm);
  proj_gemm<<<dim3(4, 136), 256, 0, stream>>>(out_perm, wph, wpl, b_proj, out);
}

// Round 17
// 335.342 us; speedup vs baseline: 2.5360x; 1.0480x over previous
//
#include <hip/hip_runtime.h>
#include <hip/hip_bf16.h>

// FrequencyAwareSumAttention — round 17: attn full-tile att_map prefetch.
// am pipeline 1-deep -> 16 float4 issued at tile start (before QK^T): HBM
// latency hides under QK^T+softmax (~2K cy) instead of one sb's ~150 cy.
// VGPR ~176->~240, same occupancy tier, NO launch_bounds (spill lesson r8/10/13).
// K0/K1/K2/K4 byte-identical to round 16 (351us build).

#define SCALE 0.125f
#define LSTR 72

typedef __attribute__((ext_vector_type(4))) float f32x4;
typedef __attribute__((ext_vector_type(8))) short bf16x8;
typedef __attribute__((ext_vector_type(8))) unsigned short u16x8;

__device__ __forceinline__ float bf2f(unsigned short u) {
  return __uint_as_float(((unsigned int)u) << 16);
}
__device__ __forceinline__ unsigned short f2bf(float f) {
  unsigned int u = __float_as_uint(f);
  u += 0x7FFFu + ((u >> 16) & 1u);
  return (unsigned short)(u >> 16);
}

// ---------------- K0a: x fp32 -> hi/lo bf16 planes ----------------
__global__ __launch_bounds__(256) void conv_x(
    const float* __restrict__ x, unsigned short* __restrict__ xh,
    unsigned short* __restrict__ xl) {
  const size_t i = ((size_t)blockIdx.x * 256 + threadIdx.x) * 8;
  float4 a = *(const float4*)(x + i);
  float4 b = *(const float4*)(x + i + 4);
  float vv[8] = {a.x, a.y, a.z, a.w, b.x, b.y, b.z, b.w};
  u16x8 hi, lo;
#pragma unroll
  for (int e = 0; e < 8; ++e) {
    unsigned short h = f2bf(vv[e]);
    hi[e] = h;
    lo[e] = f2bf(vv[e] - bf2f(h));
  }
  *(u16x8*)&xh[i] = hi;
  *(u16x8*)&xl[i] = lo;
}

// ---------------- K0b: w [K=512][N] -> transposed [N][512] hi/lo planes ----------
__global__ __launch_bounds__(256) void conv_wT(
    const float* __restrict__ w, unsigned short* __restrict__ th,
    unsigned short* __restrict__ tl, int N) {
  __shared__ float T[64][65];
  const int tid = threadIdx.x;
  const int nt = blockIdx.x * 64, kt = blockIdx.y * 64;
  for (int i = tid; i < 4096; i += 256) {
    const int r = i >> 6, c = i & 63;
    T[r][c] = w[(size_t)(kt + r) * N + nt + c];
  }
  __syncthreads();
  for (int i = tid; i < 4096; i += 256) {
    const int rn = i >> 6, ck = i & 63;
    const float v = T[ck][rn];
    const unsigned short h = f2bf(v);
    const size_t o = (size_t)(nt + rn) * 512 + kt + ck;
    th[o] = h;
    tl[o] = f2bf(v - bf2f(h));
  }
}

// ---------------- K1: qkv = x @ w_qkv (split-bf16 MFMA) -> bf16 planes ----------
// Grid: 1632 blocks (12 n-tiles x 136 m-tiles), XCD-chunk swizzled.
// m-tile = (b, jj, t0): rows share (b,jj); t = t0 + 0..127 (consecutive).
__global__ __launch_bounds__(256, 2) void qkv_gemm(
    const unsigned short* __restrict__ xh, const unsigned short* __restrict__ xl,
    const unsigned short* __restrict__ wh, const unsigned short* __restrict__ wl,
    unsigned short* __restrict__ qh, unsigned short* __restrict__ ql,
    unsigned short* __restrict__ kh, unsigned short* __restrict__ kl,
    unsigned short* __restrict__ vt) {
  __shared__ __attribute__((aligned(16))) unsigned short Wt[2][128 * LSTR];
  __shared__ __attribute__((aligned(16))) unsigned short Xt[2][128 * LSTR];

  const int tid = threadIdx.x;
  const int lin = blockIdx.x;
  const int swz = (lin & 7) * 204 + (lin >> 3);
  const int by = swz / 12, bx = swz % 12;
  const int pair = by >> 1;
  const int t0 = (by & 1) << 7;
  const int b = pair / 17;
  const int jj = pair % 17;

  const int wid = tid >> 6, lane = tid & 63;
  const int lr = lane & 15, lg = lane >> 4;
  const int wr = wid >> 1, wc = wid & 1;
  const int srow = tid >> 3, skg = tid & 7;

  const size_t xrow0 = ((size_t)((b * 256 + t0 + srow) * 17 + jj)) * 512 + skg * 8;
  const unsigned short* xhp = xh + xrow0;
  const unsigned short* xlp = xl + xrow0;
  const unsigned short* whp = wh + (size_t)(bx * 128 + srow) * 512 + skg * 8;
  const unsigned short* wlp = wl + (size_t)(bx * 128 + srow) * 512 + skg * 8;

  u16x8 rxh[4], rxl[4], rwh[4], rwl[4];
  auto loadk = [&](int k0) {
#pragma unroll
    for (int it = 0; it < 4; ++it) {
      const size_t ox = (size_t)(32 * it) * 8704 + k0;
      const size_t ow = (size_t)(32 * it) * 512 + k0;
      rxh[it] = *(const u16x8*)(xhp + ox);
      rxl[it] = *(const u16x8*)(xlp + ox);
      rwh[it] = *(const u16x8*)(whp + ow);
      rwl[it] = *(const u16x8*)(wlp + ow);
    }
  };

  f32x4 acc[4][4];
#pragma unroll
  for (int nt = 0; nt < 4; ++nt)
#pragma unroll
    for (int mt = 0; mt < 4; ++mt) acc[nt][mt] = (f32x4){0.f, 0.f, 0.f, 0.f};

  loadk(0);
  for (int s = 0; s < 8; ++s) {
    if (s) __syncthreads();
#pragma unroll
    for (int it = 0; it < 4; ++it) {
      const int base = (srow + 32 * it) * LSTR + skg * 8;
      *(u16x8*)&Xt[0][base] = rxh[it];
      *(u16x8*)&Xt[1][base] = rxl[it];
      *(u16x8*)&Wt[0][base] = rwh[it];
      *(u16x8*)&Wt[1][base] = rwl[it];
    }
    __syncthreads();
    if (s < 7) loadk((s + 1) * 64);
#pragma unroll
    for (int kh2 = 0; kh2 < 2; ++kh2) {
      const int kbase = kh2 * 32 + lg * 8;
      bf16x8 Ah[4], Al[4], Bh[4], Bl[4];
#pragma unroll
      for (int nt = 0; nt < 4; ++nt) {
        const int n = wr * 64 + nt * 16 + lr;
        Ah[nt] = *(bf16x8*)&Wt[0][n * LSTR + kbase];
        Al[nt] = *(bf16x8*)&Wt[1][n * LSTR + kbase];
      }
#pragma unroll
      for (int mt = 0; mt < 4; ++mt) {
        const int m = wc * 64 + mt * 16 + lr;
        Bh[mt] = *(bf16x8*)&Xt[0][m * LSTR + kbase];
        Bl[mt] = *(bf16x8*)&Xt[1][m * LSTR + kbase];
      }
#pragma unroll
      for (int nt = 0; nt < 4; ++nt)
#pragma unroll
        for (int mt = 0; mt < 4; ++mt) {
          acc[nt][mt] = __builtin_amdgcn_mfma_f32_16x16x32_bf16(Ah[nt], Bh[mt], acc[nt][mt], 0, 0, 0);
          acc[nt][mt] = __builtin_amdgcn_mfma_f32_16x16x32_bf16(Ah[nt], Bl[mt], acc[nt][mt], 0, 0, 0);
          acc[nt][mt] = __builtin_amdgcn_mfma_f32_16x16x32_bf16(Al[nt], Bh[mt], acc[nt][mt], 0, 0, 0);
        }
    }
  }

#pragma unroll
  for (int mt = 0; mt < 4; ++mt) {
    const int t = t0 + wc * 64 + mt * 16 + lr;
#pragma unroll
    for (int nt = 0; nt < 4; ++nt) {
      const int c = bx * 128 + wr * 64 + nt * 16 + lg * 4;
      const int qi = c >> 9;
      const int h = (c >> 6) & 7;
      const int dd = c & 63;
      const size_t hdbase = ((size_t)((b * 8 + h) * 17 + jj)) * 16384;
      float a0 = acc[nt][mt][0], a1 = acc[nt][mt][1], a2 = acc[nt][mt][2],
            a3 = acc[nt][mt][3];
      ushort4 hi4 = make_ushort4(f2bf(a0), f2bf(a1), f2bf(a2), f2bf(a3));
      if (qi == 2) {
        vt[hdbase + (size_t)(dd + 0) * 256 + t] = hi4.x;
        vt[hdbase + (size_t)(dd + 1) * 256 + t] = hi4.y;
        vt[hdbase + (size_t)(dd + 2) * 256 + t] = hi4.z;
        vt[hdbase + (size_t)(dd + 3) * 256 + t] = hi4.w;
      } else {
        ushort4 lo4 = make_ushort4(f2bf(a0 - bf2f(hi4.x)), f2bf(a1 - bf2f(hi4.y)),
                                   f2bf(a2 - bf2f(hi4.z)), f2bf(a3 - bf2f(hi4.w)));
        unsigned short* dh = qi ? kh : qh;
        unsigned short* dl = qi ? kl : ql;
        *(ushort4*)&dh[hdbase + t * 64 + dd] = hi4;
        *(ushort4*)&dl[hdbase + t * 64 + dd] = lo4;
      }
    }
  }
}

// ---------------- K2: MFMA DFT from bf16 planes + af GEMM + softmax -> af bf16 ----
__global__ __launch_bounds__(256) void freq_kernel(
    const unsigned short* __restrict__ qhp, const unsigned short* __restrict__ qlp,
    const unsigned short* __restrict__ khp, const unsigned short* __restrict__ klp,
    unsigned short* __restrict__ af_out) {
  __shared__ __attribute__((aligned(16))) unsigned short qT[2][64 * 256];
  __shared__ __attribute__((aligned(16))) unsigned short QF[4][64 * 64];
  __shared__ __attribute__((aligned(16))) unsigned short KF[4][64 * 64];

  const int tid = threadIdx.x;
  const int head = blockIdx.x;
  const int w = tid >> 6, lane = tid & 63;
  const int lr = lane & 15, lg = lane >> 4;
  const int f0 = w << 4;

  bf16x8 Ech[8], Ecl[8], Esh[8], Esl[8];
  {
    const int f = f0 + lr;
#pragma unroll
    for (int kb = 0; kb < 8; ++kb) {
      bf16x8 ch, cl, sh, sl;
#pragma unroll
      for (int i = 0; i < 8; ++i) {
        int t = kb * 32 + lg * 8 + i;
        int idx = (f * t) & 255;
        float s, c;
        __sincosf((float)idx * 0.02454369260617026f, &s, &c);
        unsigned short chh = f2bf(c);
        unsigned short shh = f2bf(s);
        ch[i] = (short)chh;
        cl[i] = (short)f2bf(c - bf2f(chh));
        sh[i] = (short)shh;
        sl[i] = (short)f2bf(s - bf2f(shh));
      }
      Ech[kb] = ch; Ecl[kb] = cl; Esh[kb] = sh; Esl[kb] = sl;
    }
  }

  for (int pass = 0; pass < 2; ++pass) {
    const unsigned short* sh_ = (pass ? khp : qhp) + head * 16384;
    const unsigned short* sl_ = (pass ? klp : qlp) + head * 16384;
    __syncthreads();
    for (int i = tid; i < 4096; i += 256) {
      int t = i >> 4, dq = i & 15;
      ushort4 hv = *(const ushort4*)&sh_[t * 64 + dq * 4];
      ushort4 lv = *(const ushort4*)&sl_[t * 64 + dq * 4];
      unsigned short hvv[4] = {hv.x, hv.y, hv.z, hv.w};
      unsigned short lvv[4] = {lv.x, lv.y, lv.z, lv.w};
#pragma unroll
      for (int c = 0; c < 4; ++c) {
        int d = dq * 4 + c;
        int byo = d * 512 + ((t * 2) ^ ((d & 31) << 4));
        *(unsigned short*)((char*)qT[0] + byo) = hvv[c];
        *(unsigned short*)((char*)qT[1] + byo) = lvv[c];
      }
    }
    __syncthreads();

    f32x4 ar[4], ai[4];
#pragma unroll
    for (int nt = 0; nt < 4; ++nt) {
      ar[nt] = (f32x4){0.f, 0.f, 0.f, 0.f};
      ai[nt] = (f32x4){0.f, 0.f, 0.f, 0.f};
    }
#pragma unroll
    for (int kb = 0; kb < 8; ++kb) {
#pragma unroll
      for (int nt = 0; nt < 4; ++nt) {
        const int d = nt * 16 + lr;
        const int byo = d * 512 + ((kb * 64 + lg * 16) ^ ((d & 31) << 4));
        bf16x8 bh = *(bf16x8*)((char*)qT[0] + byo);
        bf16x8 bl = *(bf16x8*)((char*)qT[1] + byo);
        ar[nt] = __builtin_amdgcn_mfma_f32_16x16x32_bf16(Ech[kb], bh, ar[nt], 0, 0, 0);
        ar[nt] = __builtin_amdgcn_mfma_f32_16x16x32_bf16(Ech[kb], bl, ar[nt], 0, 0, 0);
        ar[nt] = __builtin_amdgcn_mfma_f32_16x16x32_bf16(Ecl[kb], bh, ar[nt], 0, 0, 0);
        ai[nt] = __builtin_amdgcn_mfma_f32_16x16x32_bf16(Esh[kb], bh, ai[nt], 0, 0, 0);
        ai[nt] = __builtin_amdgcn_mfma_f32_16x16x32_bf16(Esh[kb], bl, ai[nt], 0, 0, 0);
        ai[nt] = __builtin_amdgcn_mfma_f32_16x16x32_bf16(Esl[kb], bh, ai[nt], 0, 0, 0);
      }
    }
    unsigned short(*DST)[64 * 64] = pass ? KF : QF;
#pragma unroll
    for (int nt = 0; nt < 4; ++nt) {
#pragma unroll
      for (int j = 0; j < 4; ++j) {
        const int f = f0 + lg * 4 + j;
        const int d = nt * 16 + lr;
        const int byo = f * 128 + ((d * 2) ^ ((f & 7) << 4));
        float vr = ar[nt][j], vi = ai[nt][j];
        unsigned short rh = f2bf(vr);
        unsigned short ih = f2bf(vi);
        *(unsigned short*)((char*)DST[0] + byo) = rh;
        *(unsigned short*)((char*)DST[1] + byo) = f2bf(vr - bf2f(rh));
        *(unsigned short*)((char*)DST[2] + byo) = ih;
        *(unsigned short*)((char*)DST[3] + byo) = f2bf(vi - bf2f(ih));
      }
    }
  }
  __syncthreads();

  f32x4 acc[4];
#pragma unroll
  for (int nt = 0; nt < 4; ++nt) acc[nt] = (f32x4){0.f, 0.f, 0.f, 0.f};
#pragma unroll
  for (int kb = 0; kb < 2; ++kb) {
    const int fA = f0 + lr;
    const int abyo = fA * 128 + ((kb * 64 + lg * 16) ^ ((fA & 7) << 4));
    bf16x8 arh = *(bf16x8*)((char*)QF[0] + abyo);
    bf16x8 arl = *(bf16x8*)((char*)QF[1] + abyo);
    bf16x8 aih = *(bf16x8*)((char*)QF[2] + abyo);
    bf16x8 ail = *(bf16x8*)((char*)QF[3] + abyo);
#pragma unroll
    for (int nt = 0; nt < 4; ++nt) {
      const int g = nt * 16 + lr;
      const int bbyo = g * 128 + ((kb * 64 + lg * 16) ^ ((g & 7) << 4));
      bf16x8 brh = *(bf16x8*)((char*)KF[0] + bbyo);
      bf16x8 brl = *(bf16x8*)((char*)KF[1] + bbyo);
      bf16x8 bih = *(bf16x8*)((char*)KF[2] + bbyo);
      bf16x8 bil = *(bf16x8*)((char*)KF[3] + bbyo);
      acc[nt] = __builtin_amdgcn_mfma_f32_16x16x32_bf16(arh, brh, acc[nt], 0, 0, 0);
      acc[nt] = __builtin_amdgcn_mfma_f32_16x16x32_bf16(arh, brl, acc[nt], 0, 0, 0);
      acc[nt] = __builtin_amdgcn_mfma_f32_16x16x32_bf16(arl, brh, acc[nt], 0, 0, 0);
      acc[nt] = __builtin_amdgcn_mfma_f32_16x16x32_bf16(aih, bih, acc[nt], 0, 0, 0);
      acc[nt] = __builtin_amdgcn_mfma_f32_16x16x32_bf16(aih, bil, acc[nt], 0, 0, 0);
      acc[nt] = __builtin_amdgcn_mfma_f32_16x16x32_bf16(ail, bih, acc[nt], 0, 0, 0);
    }
  }

  unsigned short* outh = af_out + head * 4096;
#pragma unroll
  for (int j = 0; j < 4; ++j) {
    float m = fmaxf(fmaxf(acc[0][j], acc[1][j]), fmaxf(acc[2][j], acc[3][j]));
#pragma unroll
    for (int mask = 1; mask < 16; mask <<= 1) m = fmaxf(m, __shfl_xor(m, mask));
    float e[4];
    float rs = 0.f;
#pragma unroll
    for (int nt = 0; nt < 4; ++nt) {
      e[nt] = __expf((acc[nt][j] - m) * SCALE);
      rs += e[nt];
    }
#pragma unroll
    for (int mask = 1; mask < 16; mask <<= 1) rs += __shfl_xor(rs, mask);
    const float inv = 1.0f / rs;
    const int f = f0 + lg * 4 + j;
#pragma unroll
    for (int nt = 0; nt < 4; ++nt) outh[f * 64 + nt * 16 + lr] = f2bf(e[nt] * inv);
  }
}

// ---------------- K3: attn, Wf prologue + FULL-TILE am prefetch ----------------
__global__ __launch_bounds__(256) void attn_kernel(
    const unsigned short* __restrict__ qhp, const unsigned short* __restrict__ khp,
    const unsigned short* __restrict__ vtp, const unsigned short* __restrict__ af,
    const float* __restrict__ att_map, const float* __restrict__ weight,
    const float* __restrict__ fgate, float* __restrict__ out_perm) {
  __shared__ unsigned short Ks[256 * 64];
  __shared__ unsigned short Vt[64 * 256];
  __shared__ unsigned short AFW[64 * 66];
  __shared__ unsigned short Psc[4][16 * 40];

  const int tid = threadIdx.x;
  const int head = blockIdx.x;
  const int jj = head % 17;
  const int hb = head / 17;
  const int h = hb & 7;
  const int b = hb >> 3;
  const int w = tid >> 6, lane = tid & 63;
  const int lr = lane & 15, lg = lane >> 4;

  const float* amh = att_map + (size_t)head * 65536;
  const unsigned short* qbase = qhp + head * 16384;

  const unsigned short* ksrc = khp + head * 16384;
  const unsigned short* vsrc = vtp + head * 16384;
  for (int i = tid; i < 2048; i += 256) {
    int s = i >> 3, dq8 = i & 7;
    u16x8 kv = *(const u16x8*)&ksrc[s * 64 + dq8 * 8];
    int koff = s * 128 + ((dq8 * 16) ^ ((s & 7) << 4));
    *(u16x8*)((char*)Ks + koff) = kv;
    int d = i >> 5, t8 = i & 31;
    u16x8 vv = *(const u16x8*)&vsrc[d * 256 + t8 * 8];
    int voff = d * 512 + ((t8 * 16) ^ ((d & 7) << 4));
    *(u16x8*)((char*)Vt + voff) = vv;
  }
  const unsigned short* asrc = af + head * 4096;
  for (int i = tid; i < 1024; i += 256) {
    int f = i >> 4, gq = (i & 15) << 2;
    *(ushort4*)&AFW[f * 66 + gq] = *(const ushort4*)&asrc[f * 64 + gq];
  }
  __syncthreads();

  const float wv = weight[0];
  const float gate = 1.0f / (1.0f + __expf(-fgate[0]));
  const float cg = wv * gate;
  const float cp = wv * (1.0f - gate);
  const float c2 = 1.0f - wv;
  unsigned short* psc = Psc[w];

  // ---- prologue: Wf[f][d] = sum_s AF256[f][s] * V[s][d] ----
  {
    const int fA = w * 16 + lr;
    f32x4 wacc[4];
#pragma unroll
    for (int nt = 0; nt < 4; ++nt) wacc[nt] = (f32x4){0.f, 0.f, 0.f, 0.f};
#pragma unroll
    for (int kc = 0; kc < 8; ++kc) {
      bf16x8 afr;
#pragma unroll
      for (int i = 0; i < 8; ++i) {
        const int s = kc * 32 + lg * 8 + i;
        float srcg = fmaxf((s + 0.5f) * 0.25f - 0.5f, 0.0f);
        int g0 = (int)srcg;
        float wc = srcg - (float)g0;
        int g1 = g0 + 1;
        if (g1 > 63) g1 = 63;
        float v = bf2f(AFW[fA * 66 + g0]) * (1.0f - wc) + bf2f(AFW[fA * 66 + g1]) * wc;
        afr[i] = (short)f2bf(v);
      }
      const int s0 = kc * 32 + lg * 8;
#pragma unroll
      for (int nt = 0; nt < 4; ++nt) {
        const int d = nt * 16 + lr;
        const int off = d * 512 + ((s0 * 2) ^ ((d & 7) << 4));
        bf16x8 bv = *(bf16x8*)((char*)Vt + off);
        wacc[nt] = __builtin_amdgcn_mfma_f32_16x16x32_bf16(afr, bv, wacc[nt], 0, 0, 0);
      }
    }
    __syncthreads();
#pragma unroll
    for (int nt = 0; nt < 4; ++nt) {
#pragma unroll
      for (int j = 0; j < 4; ++j) {
        AFW[(w * 16 + lg * 4 + j) * 66 + nt * 16 + lr] = f2bf(wacc[nt][j]);
      }
    }
    __syncthreads();
  }

  bf16x8 rq[2];
  {
    const unsigned short* qrow = qbase + (w * 64 + lr) * 64 + lg * 8;
    rq[0] = *(const bf16x8*)(qrow);
    rq[1] = *(const bf16x8*)(qrow + 32);
  }

  for (int tt = 0; tt < 4; ++tt) {
    const int tw = w * 64 + tt * 16;
    const float* amrow = amh + (size_t)(tw + lr) * 256 + lg * 8;

    // ---- FULL-TILE am prefetch: 16 float4 issued before QK^T ----
    float4 amr[16];
#pragma unroll
    for (int sb = 0; sb < 8; ++sb) {
      amr[sb * 2 + 0] = *(const float4*)(amrow + sb * 32);
      amr[sb * 2 + 1] = *(const float4*)(amrow + sb * 32 + 4);
    }

    bf16x8 aq[2] = {rq[0], rq[1]};

    // ---- QK^T ----
    f32x4 S[16];
#pragma unroll
    for (int nt = 0; nt < 16; ++nt) {
      f32x4 accv = {0.f, 0.f, 0.f, 0.f};
#pragma unroll
      for (int kc = 0; kc < 2; ++kc) {
        int srow = nt * 16 + lr;
        int d0 = kc * 32 + lg * 8;
        int off = srow * 128 + ((d0 * 2) ^ ((srow & 7) << 4));
        bf16x8 bk = *(bf16x8*)((char*)Ks + off);
        accv = __builtin_amdgcn_mfma_f32_16x16x32_bf16(aq[kc], bk, accv, 0, 0, 0);
      }
      S[nt] = accv;
    }

    if (tt < 3) {
      const unsigned short* qrow = qbase + (tw + 16 + lr) * 64 + lg * 8;
      rq[0] = *(const bf16x8*)(qrow);
      rq[1] = *(const bf16x8*)(qrow + 32);
    }

    // ---- softmax (16-lane xor groups) ----
    float c1j[4];
#pragma unroll
    for (int j = 0; j < 4; ++j) {
      float m = -1e30f;
#pragma unroll
      for (int nt = 0; nt < 16; ++nt) m = fmaxf(m, S[nt][j]);
#pragma unroll
      for (int mask = 1; mask < 16; mask <<= 1) m = fmaxf(m, __shfl_xor(m, mask));
      float rs = 0.f;
#pragma unroll
      for (int nt = 0; nt < 16; ++nt) {
        float e = __expf((S[nt][j] - m) * SCALE);
        S[nt][j] = e;
        rs += e;
      }
#pragma unroll
      for (int mask = 1; mask < 16; mask <<= 1) rs += __shfl_xor(rs, mask);
      c1j[j] = cp / rs;
    }

    // ---- PV with am folded into A-frag (am already in registers) ----
    f32x4 O[4];
#pragma unroll
    for (int dt = 0; dt < 4; ++dt) O[dt] = (f32x4){0.f, 0.f, 0.f, 0.f};
#pragma unroll
    for (int sb = 0; sb < 8; ++sb) {
#pragma unroll
      for (int half = 0; half < 2; ++half) {
        const int nt = sb * 2 + half;
#pragma unroll
        for (int j = 0; j < 4; ++j) {
          psc[(lg * 4 + j) * 40 + half * 16 + lr] = f2bf(c1j[j] * S[nt][j]);
        }
      }
      bf16x8 praw = *(bf16x8*)&psc[lr * 40 + lg * 8];
      bf16x8 pa;
      {
        const float4 a0 = amr[sb * 2 + 0];
        const float4 a1 = amr[sb * 2 + 1];
        float av[8] = {a0.x, a0.y, a0.z, a0.w, a1.x, a1.y, a1.z, a1.w};
#pragma unroll
        for (int i = 0; i < 8; ++i) {
          pa[i] = (short)f2bf(bf2f((unsigned short)praw[i]) + c2 * av[i]);
        }
      }
      const int s0 = sb * 32 + lg * 8;
#pragma unroll
      for (int dt = 0; dt < 4; ++dt) {
        const int d = dt * 16 + lr;
        int off = d * 512 + ((s0 * 2) ^ ((d & 7) << 4));
        bf16x8 bv = *(bf16x8*)((char*)Vt + off);
        O[dt] = __builtin_amdgcn_mfma_f32_16x16x32_bf16(pa, bv, O[dt], 0, 0, 0);
      }
    }

    // ---- add freq term via Wf interp + write out_perm ----
#pragma unroll
    for (int j = 0; j < 4; ++j) {
      const int t = tw + lg * 4 + j;
      float srcf = fmaxf((t + 0.5f) * (129.0f / 256.0f) - 0.5f, 0.0f);
      int f0r = (int)srcf;
      float wf = srcf - (float)f0r;
      int f1r = f0r + 1;
      const bool v0 = (f0r < 64), v1 = (f1r < 64);
      float* orow = out_perm + ((size_t)((b * 256 + t) * 17 + jj)) * 512 + h * 64;
#pragma unroll
      for (int dt = 0; dt < 4; ++dt) {
        const int d = dt * 16 + lr;
        float fv = 0.f;
        if (v0) fv += (1.0f - wf) * bf2f(AFW[f0r * 66 + d]);
        if (v1) fv += wf * bf2f(AFW[f1r * 66 + d]);
        orow[d] = O[dt][j] + cg * fv;
      }
    }
  }
}

// ---------------- K4: d_out = out_perm @ w_proj + b_proj (split-bf16 MFMA) --------
__global__ __launch_bounds__(256, 2) void proj_gemm(
    const float* __restrict__ A,
    const unsigned short* __restrict__ wh, const unsigned short* __restrict__ wl,
    const float* __restrict__ bias, float* __restrict__ out) {
  __shared__ __attribute__((aligned(16))) unsigned short Wt[2][128 * LSTR];
  __shared__ __attribute__((aligned(16))) unsigned short Xt[2][128 * LSTR];

  const int tid = threadIdx.x;
  const int bx = blockIdx.x, by = blockIdx.y;
  const int wid = tid >> 6, lane = tid & 63;
  const int lr = lane & 15, lg = lane >> 4;
  const int wr = wid >> 1, wc = wid & 1;
  const int srow = tid >> 3, skg = tid & 7;

  const float* ap = A + (size_t)(by * 128 + srow) * 512 + skg * 8;
  const unsigned short* whp = wh + (size_t)(bx * 128 + srow) * 512 + skg * 8;
  const unsigned short* wlp = wl + (size_t)(bx * 128 + srow) * 512 + skg * 8;

  float4 rA[4][2];
  u16x8 rwh[4], rwl[4];
  auto loadk = [&](int k0) {
#pragma unroll
    for (int it = 0; it < 4; ++it) {
      const size_t o = (size_t)(32 * it) * 512 + k0;
      rA[it][0] = *(const float4*)(ap + o);
      rA[it][1] = *(const float4*)(ap + o + 4);
      rwh[it] = *(const u16x8*)(whp + o);
      rwl[it] = *(const u16x8*)(wlp + o);
    }
  };

  f32x4 acc[4][4];
#pragma unroll
  for (int nt = 0; nt < 4; ++nt)
#pragma unroll
    for (int mt = 0; mt < 4; ++mt) acc[nt][mt] = (f32x4){0.f, 0.f, 0.f, 0.f};

  loadk(0);
  for (int s = 0; s < 8; ++s) {
    if (s) __syncthreads();
#pragma unroll
    for (int it = 0; it < 4; ++it) {
      const int base = (srow + 32 * it) * LSTR + skg * 8;
      float vv[8] = {rA[it][0].x, rA[it][0].y, rA[it][0].z, rA[it][0].w,
                     rA[it][1].x, rA[it][1].y, rA[it][1].z, rA[it][1].w};
      u16x8 hi, lo;
#pragma unroll
      for (int e = 0; e < 8; ++e) {
        unsigned short h = f2bf(vv[e]);
        hi[e] = h;
        lo[e] = f2bf(vv[e] - bf2f(h));
      }
      *(u16x8*)&Xt[0][base] = hi;
      *(u16x8*)&Xt[1][base] = lo;
      *(u16x8*)&Wt[0][base] = rwh[it];
      *(u16x8*)&Wt[1][base] = rwl[it];
    }
    __syncthreads();
    if (s < 7) loadk((s + 1) * 64);
#pragma unroll
    for (int kh2 = 0; kh2 < 2; ++kh2) {
      const int kbase = kh2 * 32 + lg * 8;
      bf16x8 Ah[4], Al[4], Bh[4], Bl[4];
#pragma unroll
      for (int nt = 0; nt < 4; ++nt) {
        const int n = wr * 64 + nt * 16 + lr;
        Ah[nt] = *(bf16x8*)&Wt[0][n * LSTR + kbase];
        Al[nt] = *(bf16x8*)&Wt[1][n * LSTR + kbase];
      }
#pragma unroll
      for (int mt = 0; mt < 4; ++mt) {
        const int m = wc * 64 + mt * 16 + lr;
        Bh[mt] = *(bf16x8*)&Xt[0][m * LSTR + kbase];
        Bl[mt] = *(bf16x8*)&Xt[1][m * LSTR + kbase];
      }
#pragma unroll
      for (int nt = 0; nt < 4; ++nt)
#pragma unroll
        for (int mt = 0; mt < 4; ++mt) {
          acc[nt][mt] = __builtin_amdgcn_mfma_f32_16x16x32_bf16(Ah[nt], Bh[mt], acc[nt][mt], 0, 0, 0);
          acc[nt][mt] = __builtin_amdgcn_mfma_f32_16x16x32_bf16(Ah[nt], Bl[mt], acc[nt][mt], 0, 0, 0);
          acc[nt][mt] = __builtin_amdgcn_mfma_f32_16x16x32_bf16(Al[nt], Bh[mt], acc[nt][mt], 0, 0, 0);
        }
    }
  }

#pragma unroll
  for (int mt = 0; mt < 4; ++mt) {
    const int m = by * 128 + wc * 64 + mt * 16 + lr;
#pragma unroll
    for (int nt = 0; nt < 4; ++nt) {
      const int n = bx * 128 + wr * 64 + nt * 16 + lg * 4;
      float4 bi = *(const float4*)&bias[n];
      *(float4*)&out[(size_t)m * 512 + n] =
          make_float4(acc[nt][mt][0] + bi.x, acc[nt][mt][1] + bi.y,
                      acc[nt][mt][2] + bi.z, acc[nt][mt][3] + bi.w);
    }
  }
}

extern "C" void kernel_launch(void* const* d_in, const int* in_sizes, int n_in,
                              void* d_out, int out_size, void* d_ws, size_t ws_size,
                              hipStream_t stream) {
  (void)in_sizes; (void)n_in; (void)out_size; (void)ws_size;
  const float* x = (const float*)d_in[0];
  const float* att_map = (const float*)d_in[1];
  const float* weight = (const float*)d_in[2];
  const float* w_qkv = (const float*)d_in[3];
  const float* w_proj = (const float*)d_in[4];
  const float* b_proj = (const float*)d_in[5];
  const float* fgate = (const float*)d_in[6];
  float* out = (float*)d_out;

  char* ws = (char*)d_ws;
  const size_t PB = 17825792;  // one bf16 plane: 544*16384*2 B
  unsigned short* qh = (unsigned short*)(ws);
  unsigned short* ql = (unsigned short*)(ws + PB);
  unsigned short* kh = (unsigned short*)(ws + 2 * PB);
  unsigned short* kl = (unsigned short*)(ws + 3 * PB);
  unsigned short* vt = (unsigned short*)(ws + 4 * PB);
  unsigned short* af = (unsigned short*)(ws + 5 * PB);  // 544*4096 bf16
  char* base = ws + 5 * PB + 4456448;
  unsigned short* xh = (unsigned short*)(base);
  unsigned short* xl = (unsigned short*)(base + PB);
  float* out_perm = (float*)(base);  // alias xh/xl (disjoint lifetimes)
  unsigned short* wqh = (unsigned short*)(base + 35651584);
  unsigned short* wql = (unsigned short*)(base + 35651584 + 1572864);
  unsigned short* wph = (unsigned short*)(base + 35651584 + 2 * 1572864);
  unsigned short* wpl = (unsigned short*)(base + 35651584 + 2 * 1572864 + 524288);

  conv_x<<<4352, 256, 0, stream>>>(x, xh, xl);
  conv_wT<<<dim3(24, 8), 256, 0, stream>>>(w_qkv, wqh, wql, 1536);
  conv_wT<<<dim3(8, 8), 256, 0, stream>>>(w_proj, wph, wpl, 512);
  qkv_gemm<<<1632, 256, 0, stream>>>(xh, xl, wqh, wql, qh, ql, kh, kl, vt);
  freq_kernel<<<544, 256, 0, stream>>>(qh, ql, kh, kl, af);
  attn_kernel<<<544, 256, 0, stream>>>(qh, kh, vt, af, att_map, weight, fgate,
                                       out_perm);
  proj_gemm<<<dim3(4, 136), 256, 0, stream>>>(out_perm, wph, wpl, b_proj, out);
}